// Round 5
// baseline (403.971 us; speedup 1.0000x reference)
//
#include <hip/hip_runtime.h>

// GCN 3-layer, fused:
// K1: a1 = dis.*agg(x.*dis)  ->  h1 = relu(a1@W1+b1)           (fused agg+rowGEMM)
// K2: g2 = (h1@W2).*dis                                         (reg-tiled GEMM)
// K3: acc = agg128(g2); h2 = relu(dis.*acc+b2); g3=(h2@W3).*dis (fused agg+rowGEMM)
// K4: out = dis.*agg(g3) + b3
// dis[i] = rsqrt(1 + indegree[i])

// ---------------- graph preprocessing ----------------

__global__ void count_kernel(const int* __restrict__ dst, int* __restrict__ count, int e) {
    int i = blockIdx.x * blockDim.x + threadIdx.x;
    if (i < e) atomicAdd(&count[dst[i]], 1);
}

// single-block exclusive scan (+ dis computation): 1024 threads x 64 elements in registers
__global__ __launch_bounds__(1024) void scan_kernel(const int* __restrict__ count,
                                                    int* __restrict__ offsets,
                                                    int* __restrict__ cursor,
                                                    float* __restrict__ dis, int n) {
    constexpr int T = 64;  // covers n <= 65536
    __shared__ int wsum[16];
    int tid = threadIdx.x;
    int lane = tid & 63, wid = tid >> 6;
    int base = tid * T;

    int v[T];
    int tot = 0;
    if (base + T <= n) {
        #pragma unroll
        for (int j = 0; j < T; j += 4) {
            int4 c4 = *reinterpret_cast<const int4*>(count + base + j);
            v[j + 0] = tot; tot += c4.x;
            v[j + 1] = tot; tot += c4.y;
            v[j + 2] = tot; tot += c4.z;
            v[j + 3] = tot; tot += c4.w;
            float4 d4 = make_float4(rsqrtf((float)(c4.x + 1)), rsqrtf((float)(c4.y + 1)),
                                    rsqrtf((float)(c4.z + 1)), rsqrtf((float)(c4.w + 1)));
            *reinterpret_cast<float4*>(dis + base + j) = d4;
        }
    } else {
        #pragma unroll
        for (int j = 0; j < T; ++j) {
            int idx = base + j;
            int c = (idx < n) ? count[idx] : 0;
            if (idx < n) dis[idx] = rsqrtf((float)(c + 1));
            v[j] = tot; tot += c;
        }
    }

    int x = tot;
    #pragma unroll
    for (int d = 1; d < 64; d <<= 1) {
        int t = __shfl_up(x, d, 64);
        if (lane >= d) x += t;
    }
    if (lane == 63) wsum[wid] = x;
    __syncthreads();
    if (wid == 0 && lane < 16) {
        int wv = wsum[lane];
        #pragma unroll
        for (int d = 1; d < 16; d <<= 1) {
            int t = __shfl_up(wv, d, 64);
            if (lane >= d) wv += t;
        }
        wsum[lane] = wv;
    }
    __syncthreads();
    int waveExcl = (wid == 0) ? 0 : wsum[wid - 1];
    int tbase = waveExcl + (x - tot);

    if (base + T <= n) {
        #pragma unroll
        for (int j = 0; j < T; j += 4) {
            int4 o4 = make_int4(tbase + v[j], tbase + v[j + 1], tbase + v[j + 2], tbase + v[j + 3]);
            *reinterpret_cast<int4*>(offsets + base + j) = o4;
            *reinterpret_cast<int4*>(cursor + base + j) = o4;
        }
    } else {
        #pragma unroll
        for (int j = 0; j < T; ++j) {
            int idx = base + j;
            if (idx < n) { offsets[idx] = tbase + v[j]; cursor[idx] = tbase + v[j]; }
        }
    }
    if (tid == 1023) offsets[n] = tbase + tot;
}

__global__ void fill_kernel(const int* __restrict__ src, const int* __restrict__ dst,
                            int* __restrict__ cursor, int* __restrict__ srcs_sorted, int e) {
    int i = blockIdx.x * blockDim.x + threadIdx.x;
    if (i < e) {
        int d = dst[i];
        int pos = atomicAdd(&cursor[d], 1);
        srcs_sorted[pos] = src[i];
    }
}

// ---------------- K1: agg64(x, dis-weighted) + rowGEMM W1(64x128) + bias + relu ----------------

__global__ __launch_bounds__(256) void fused_l1(const float* __restrict__ x,
                                                const int* __restrict__ srcs,
                                                const int* __restrict__ offsets,
                                                const float* __restrict__ dis,
                                                const float* __restrict__ W1,
                                                const float* __restrict__ b1,
                                                float* __restrict__ h1, int n) {
    __shared__ float wlds[64 * 128];   // W1 row-major [k][c], 32 KB
    __shared__ float arow[4][64];      // per-wave a1 row
    for (int idx = threadIdx.x * 4; idx < 64 * 128; idx += 1024)
        *reinterpret_cast<float4*>(&wlds[idx]) = *reinterpret_cast<const float4*>(&W1[idx]);
    __syncthreads();

    int wid = threadIdx.x >> 6, lane = threadIdx.x & 63;
    int i = blockIdx.x * 4 + wid;
    if (i >= n) return;  // exact grid for n%4==0; no barriers below

    int grp = lane >> 4, cl = lane & 15, c = cl * 4;
    const float* gc = x + c;
    float di = dis[i];
    int e0 = offsets[i], e1 = offsets[i + 1];
    int e = e0;

    float4 a0 = make_float4(0.f, 0.f, 0.f, 0.f), a1v = a0;
    if (grp == 0) {
        float4 sf = *reinterpret_cast<const float4*>(gc + (size_t)i * 64);
        a0 = make_float4(sf.x * di, sf.y * di, sf.z * di, sf.w * di);
    }
    for (; e + 8 <= e1; e += 8) {
        int s0 = srcs[e + grp], s1 = srcs[e + 4 + grp];
        float4 l0 = *reinterpret_cast<const float4*>(gc + (size_t)s0 * 64);
        float4 l1 = *reinterpret_cast<const float4*>(gc + (size_t)s1 * 64);
        float w0 = dis[s0], w1 = dis[s1];
        a0.x += l0.x * w0; a0.y += l0.y * w0; a0.z += l0.z * w0; a0.w += l0.w * w0;
        a1v.x += l1.x * w1; a1v.y += l1.y * w1; a1v.z += l1.z * w1; a1v.w += l1.w * w1;
    }
    if (e + 4 <= e1) {
        int s0 = srcs[e + grp];
        float4 l0 = *reinterpret_cast<const float4*>(gc + (size_t)s0 * 64);
        float w0 = dis[s0];
        a0.x += l0.x * w0; a0.y += l0.y * w0; a0.z += l0.z * w0; a0.w += l0.w * w0;
        e += 4;
    }
    int rem = e1 - e;
    if (grp < rem) {
        int s0 = srcs[e + grp];
        float4 l0 = *reinterpret_cast<const float4*>(gc + (size_t)s0 * 64);
        float w0 = dis[s0];
        a1v.x += l0.x * w0; a1v.y += l0.y * w0; a1v.z += l0.z * w0; a1v.w += l0.w * w0;
    }

    float4 acc = make_float4(a0.x + a1v.x, a0.y + a1v.y, a0.z + a1v.z, a0.w + a1v.w);
    #pragma unroll
    for (int d = 16; d <= 32; d <<= 1) {
        acc.x += __shfl_xor(acc.x, d, 64);
        acc.y += __shfl_xor(acc.y, d, 64);
        acc.z += __shfl_xor(acc.z, d, 64);
        acc.w += __shfl_xor(acc.w, d, 64);
    }
    if (grp == 0) {
        float4 o = make_float4(di * acc.x, di * acc.y, di * acc.z, di * acc.w);
        *reinterpret_cast<float4*>(&arow[wid][c]) = o;
    }
    // intra-wave LDS turnaround: compiler inserts lgkmcnt wait on the dependency

    float accA = b1[lane], accB = b1[lane + 64];
    #pragma unroll 8
    for (int k = 0; k < 64; ++k) {
        float av = arow[wid][k];                 // broadcast
        accA += av * wlds[k * 128 + lane];       // 2-way bank alias = free
        accB += av * wlds[k * 128 + 64 + lane];
    }
    h1[(size_t)i * 128 + lane] = fmaxf(accA, 0.f);
    h1[(size_t)i * 128 + 64 + lane] = fmaxf(accB, 0.f);
}

// ---------------- K3: agg128(g2, prescaled) + bias/relu + rowGEMM W3(128x64) + dis scale ----

__global__ __launch_bounds__(256) void fused_l3(const float* __restrict__ g2,
                                                const int* __restrict__ srcs,
                                                const int* __restrict__ offsets,
                                                const float* __restrict__ dis,
                                                const float* __restrict__ W3,
                                                const float* __restrict__ b2,
                                                float* __restrict__ g3, int n) {
    __shared__ float wlds[128 * 64];   // W3 row-major [k][c], 32 KB
    __shared__ float hrow[4][128];     // per-wave h2 row
    for (int idx = threadIdx.x * 4; idx < 128 * 64; idx += 1024)
        *reinterpret_cast<float4*>(&wlds[idx]) = *reinterpret_cast<const float4*>(&W3[idx]);
    __syncthreads();

    int wid = threadIdx.x >> 6, lane = threadIdx.x & 63;
    int i = blockIdx.x * 4 + wid;
    if (i >= n) return;

    int half = lane >> 5, cl = lane & 31, c = cl * 4;
    const float* gc = g2 + c;
    float di = dis[i];
    int e0 = offsets[i], e1 = offsets[i + 1];
    int e = e0;

    float4 a0 = make_float4(0.f, 0.f, 0.f, 0.f), a1v = a0;
    if (half == 0) {
        a0 = *reinterpret_cast<const float4*>(gc + (size_t)i * 128);
    }
    for (; e + 4 <= e1; e += 4) {
        int s0 = srcs[e + half], s1 = srcs[e + 2 + half];
        float4 l0 = *reinterpret_cast<const float4*>(gc + (size_t)s0 * 128);
        float4 l1 = *reinterpret_cast<const float4*>(gc + (size_t)s1 * 128);
        a0.x += l0.x; a0.y += l0.y; a0.z += l0.z; a0.w += l0.w;
        a1v.x += l1.x; a1v.y += l1.y; a1v.z += l1.z; a1v.w += l1.w;
    }
    if (e + 2 <= e1) {
        int s0 = srcs[e + half];
        float4 l0 = *reinterpret_cast<const float4*>(gc + (size_t)s0 * 128);
        a0.x += l0.x; a0.y += l0.y; a0.z += l0.z; a0.w += l0.w;
        e += 2;
    }
    if (e < e1 && half == 0) {
        int s0 = srcs[e];
        float4 l0 = *reinterpret_cast<const float4*>(gc + (size_t)s0 * 128);
        a1v.x += l0.x; a1v.y += l0.y; a1v.z += l0.z; a1v.w += l0.w;
    }

    float4 acc = make_float4(a0.x + a1v.x, a0.y + a1v.y, a0.z + a1v.z, a0.w + a1v.w);
    acc.x += __shfl_xor(acc.x, 32, 64);
    acc.y += __shfl_xor(acc.y, 32, 64);
    acc.z += __shfl_xor(acc.z, 32, 64);
    acc.w += __shfl_xor(acc.w, 32, 64);

    if (half == 0) {
        float4 b = *reinterpret_cast<const float4*>(b2 + c);
        float4 o = make_float4(fmaxf(di * acc.x + b.x, 0.f), fmaxf(di * acc.y + b.y, 0.f),
                               fmaxf(di * acc.z + b.z, 0.f), fmaxf(di * acc.w + b.w, 0.f));
        *reinterpret_cast<float4*>(&hrow[wid][c]) = o;
    }
    // intra-wave LDS turnaround

    float accC = 0.f;
    #pragma unroll 8
    for (int k = 0; k < 128; ++k) {
        float hv = hrow[wid][k];                 // broadcast
        accC += hv * wlds[k * 64 + lane];        // 2-way bank alias = free
    }
    g3[(size_t)i * 64 + lane] = accC * di;
}

// ---------------- K4: aggregate (C=64, prescaled, +bias) ----------------

__global__ __launch_bounds__(256) void aggregate64(const float* __restrict__ g,
                                                   const int* __restrict__ srcs,
                                                   const int* __restrict__ offsets,
                                                   const float* __restrict__ dis,
                                                   const float* __restrict__ bias,
                                                   float* __restrict__ out, int n) {
    int wid = threadIdx.x >> 6, lane = threadIdx.x & 63;
    int i = blockIdx.x * 4 + wid;
    if (i >= n) return;
    float di = dis[i];
    int e0 = offsets[i], e1 = offsets[i + 1];
    int e = e0;

    int grp = lane >> 4, cl = lane & 15, c = cl * 4;
    const float* gc = g + c;
    float4 a0 = make_float4(0.f, 0.f, 0.f, 0.f), a1v = a0;

    if (grp == 0) a0 = *reinterpret_cast<const float4*>(gc + (size_t)i * 64);

    for (; e + 8 <= e1; e += 8) {
        int s0 = srcs[e + grp], s1 = srcs[e + 4 + grp];
        float4 l0 = *reinterpret_cast<const float4*>(gc + (size_t)s0 * 64);
        float4 l1 = *reinterpret_cast<const float4*>(gc + (size_t)s1 * 64);
        a0.x += l0.x; a0.y += l0.y; a0.z += l0.z; a0.w += l0.w;
        a1v.x += l1.x; a1v.y += l1.y; a1v.z += l1.z; a1v.w += l1.w;
    }
    if (e + 4 <= e1) {
        int s0 = srcs[e + grp];
        float4 l0 = *reinterpret_cast<const float4*>(gc + (size_t)s0 * 64);
        a0.x += l0.x; a0.y += l0.y; a0.z += l0.z; a0.w += l0.w;
        e += 4;
    }
    int rem = e1 - e;
    if (grp < rem) {
        int s0 = srcs[e + grp];
        float4 l0 = *reinterpret_cast<const float4*>(gc + (size_t)s0 * 64);
        a1v.x += l0.x; a1v.y += l0.y; a1v.z += l0.z; a1v.w += l0.w;
    }

    float4 acc = make_float4(a0.x + a1v.x, a0.y + a1v.y, a0.z + a1v.z, a0.w + a1v.w);
    #pragma unroll
    for (int d = 16; d <= 32; d <<= 1) {
        acc.x += __shfl_xor(acc.x, d, 64);
        acc.y += __shfl_xor(acc.y, d, 64);
        acc.z += __shfl_xor(acc.z, d, 64);
        acc.w += __shfl_xor(acc.w, d, 64);
    }
    if (grp == 0) {
        float4 b = *reinterpret_cast<const float4*>(bias + c);
        float4 o = make_float4(di * acc.x + b.x, di * acc.y + b.y,
                               di * acc.z + b.z, di * acc.w + b.w);
        *reinterpret_cast<float4*>(out + (size_t)i * 64 + c) = o;
    }
}

// ---------------- K2: reg-tiled GEMM, out = (in@W)*dis ----------------

template<int CIN, int COUT, int RPT>
__global__ __launch_bounds__(256) void gemm_scale(const float* __restrict__ in,
                                                  const float* __restrict__ W,
                                                  const float* __restrict__ dis,
                                                  float* __restrict__ out, int n) {
    constexpr int G = COUT / 4;
    constexpr int TY = 256 / G;
    constexpr int R = TY * RPT;
    __shared__ float wlds[CIN * COUT];
    for (int idx = threadIdx.x * 4; idx < CIN * COUT; idx += 1024)
        *reinterpret_cast<float4*>(&wlds[idx]) = *reinterpret_cast<const float4*>(&W[idx]);
    __syncthreads();

    int tx = threadIdx.x % G;
    int ty = threadIdx.x / G;
    int c0 = tx * 4;
    int rowBase = blockIdx.x * R + ty * RPT;

    int r[RPT];
    #pragma unroll
    for (int j = 0; j < RPT; ++j) r[j] = min(rowBase + j, n - 1);

    float4 acc[RPT];
    #pragma unroll
    for (int j = 0; j < RPT; ++j) acc[j] = make_float4(0.f, 0.f, 0.f, 0.f);

    #pragma unroll 2
    for (int k = 0; k < CIN; k += 4) {
        float4 w0 = *reinterpret_cast<const float4*>(&wlds[(k + 0) * COUT + c0]);
        float4 w1 = *reinterpret_cast<const float4*>(&wlds[(k + 1) * COUT + c0]);
        float4 w2 = *reinterpret_cast<const float4*>(&wlds[(k + 2) * COUT + c0]);
        float4 w3 = *reinterpret_cast<const float4*>(&wlds[(k + 3) * COUT + c0]);
        #pragma unroll
        for (int j = 0; j < RPT; ++j) {
            float4 a = *reinterpret_cast<const float4*>(in + (size_t)r[j] * CIN + k);
            acc[j].x += a.x * w0.x + a.y * w1.x + a.z * w2.x + a.w * w3.x;
            acc[j].y += a.x * w0.y + a.y * w1.y + a.z * w2.y + a.w * w3.y;
            acc[j].z += a.x * w0.z + a.y * w1.z + a.z * w2.z + a.w * w3.z;
            acc[j].w += a.x * w0.w + a.y * w1.w + a.z * w2.w + a.w * w3.w;
        }
    }

    #pragma unroll
    for (int j = 0; j < RPT; ++j) {
        if (rowBase + j < n) {
            float d = dis[r[j]];
            float4 o = make_float4(acc[j].x * d, acc[j].y * d, acc[j].z * d, acc[j].w * d);
            *reinterpret_cast<float4*>(out + (size_t)r[j] * COUT + c0) = o;
        }
    }
}

// ---------------- launch ----------------

extern "C" void kernel_launch(void* const* d_in, const int* in_sizes, int n_in,
                              void* d_out, int out_size, void* d_ws, size_t ws_size,
                              hipStream_t stream) {
    const float* x  = (const float*)d_in[0];
    const int*   ei = (const int*)d_in[1];
    const float* W1 = (const float*)d_in[2];
    const float* b1 = (const float*)d_in[3];
    const float* W2 = (const float*)d_in[4];
    const float* b2 = (const float*)d_in[5];
    const float* W3 = (const float*)d_in[6];
    const float* b3 = (const float*)d_in[7];
    float* out = (float*)d_out;

    const int n = in_sizes[0] / 64;   // 50000
    const int e = in_sizes[1] / 2;    // 800000
    const int* src = ei;
    const int* dst = ei + e;

    // workspace layout (4-byte units)
    int*   ws_i = (int*)d_ws;
    float* ws_f = (float*)d_ws;
    size_t o = 0;
    int* count   = ws_i + o; o += n;
    int* offsets = ws_i + o; o += n + 8;
    int* cursor  = ws_i + o; o += n;
    int* srcs    = ws_i + o; o += e;
    float* dis   = ws_f + o; o += n;
    o = (o + 3) & ~(size_t)3;
    float* bufA  = ws_f + o; o += (size_t)n * 128;
    float* bufB  = ws_f + o; o += (size_t)n * 128;

    const int B = 256;
    hipMemsetAsync(count, 0, (size_t)n * sizeof(int), stream);
    count_kernel<<<(e + B - 1) / B, B, 0, stream>>>(dst, count, e);
    scan_kernel<<<1, 1024, 0, stream>>>(count, offsets, cursor, dis, n);
    fill_kernel<<<(e + B - 1) / B, B, 0, stream>>>(src, dst, cursor, srcs, e);

    dim3 agrid((n + 3) / 4);

    // K1: agg(x)+W1+b1+relu -> h1 (bufB, 128-wide)
    fused_l1<<<agrid, 256, 0, stream>>>(x, srcs, offsets, dis, W1, b1, bufB, n);
    // K2: g2 = (h1@W2)*dis -> bufA
    gemm_scale<128, 128, 8><<<(n + 63) / 64, 256, 0, stream>>>(bufB, W2, dis, bufA, n);
    // K3: agg128(g2)+b2+relu+W3+dis -> g3 (bufB, 64-wide)
    fused_l3<<<agrid, 256, 0, stream>>>(bufA, srcs, offsets, dis, W3, b2, bufB, n);
    // K4: out = dis*agg(g3)+b3
    aggregate64<<<agrid, 256, 0, stream>>>(bufB, srcs, offsets, dis, b3, out, n);
}

// Round 6
// 289.337 us; speedup vs baseline: 1.3962x; 1.3962x over previous
//
#include <hip/hip_runtime.h>
#include <hip/hip_fp16.h>

// GCN 3-layer, fp16 message payloads (f32 accumulate):
// prep: x16 = half(x .* dis)
// L1: a1 = dis.*agg(x16)            ; h1 = relu(a1@W1+b1)        [agg64h + gemm EPI1]
// L2: g2 = half((h1@W2).*dis)       ; h2 = relu(dis.*agg(g2)+b2) [gemm EPI0 + agg128h]
// L3: g3 = half((h2@W3).*dis)       ; out = dis.*agg(g3)+b3      [gemm EPI0 + agg64h]
// dis[i] = rsqrt(1 + indegree[i])

struct alignas(8) Half4 { __half2 lo, hi; };

__device__ inline float4 h4_to_f4(Half4 h) {
    float2 a = __half22float2(h.lo), b = __half22float2(h.hi);
    return make_float4(a.x, a.y, b.x, b.y);
}
__device__ inline Half4 f4_to_h4(float4 v) {
    Half4 h; h.lo = __floats2half2_rn(v.x, v.y); h.hi = __floats2half2_rn(v.z, v.w); return h;
}

// ---------------- graph preprocessing ----------------

__global__ void count_kernel(const int* __restrict__ dst, int* __restrict__ count, int e) {
    int i = blockIdx.x * blockDim.x + threadIdx.x;
    if (i < e) atomicAdd(&count[dst[i]], 1);
}

// per-1024-chunk sums
__global__ __launch_bounds__(256) void partial_kernel(const int* __restrict__ count,
                                                      int* __restrict__ partial, int n) {
    int b = blockIdx.x, tid = threadIdx.x;
    int idx = b * 1024 + tid * 4;
    int s = 0;
    if (idx + 4 <= n) {
        int4 c = *reinterpret_cast<const int4*>(count + idx);
        s = c.x + c.y + c.z + c.w;
    } else {
        for (int j = 0; j < 4; ++j) if (idx + j < n) s += count[idx + j];
    }
    #pragma unroll
    for (int d = 1; d < 64; d <<= 1) s += __shfl_xor(s, d, 64);
    __shared__ int wred[4];
    int lane = tid & 63, wid = tid >> 6;
    if (lane == 0) wred[wid] = s;
    __syncthreads();
    if (tid == 0) partial[b] = wred[0] + wred[1] + wred[2] + wred[3];
}

// exclusive scan of P partials (single wave); writes offsets[n] = total
__global__ void scan_partials_kernel(const int* __restrict__ partial, int* __restrict__ pscan,
                                     int* __restrict__ offsets, int n, int P) {
    int lane = threadIdx.x;  // 64 threads
    int running = 0;
    for (int base = 0; base < P; base += 64) {
        int idx = base + lane;
        int v = (idx < P) ? partial[idx] : 0;
        int x = v;
        #pragma unroll
        for (int d = 1; d < 64; d <<= 1) {
            int t = __shfl_up(x, d, 64);
            if (lane >= d) x += t;
        }
        if (idx < P) pscan[idx] = running + x - v;
        running += __shfl(x, 63, 64);
    }
    if (lane == 0) offsets[n] = running;
}

// per-chunk: local scan + base -> offsets/cursor; also dis
__global__ __launch_bounds__(256) void apply_kernel(const int* __restrict__ count,
                                                    const int* __restrict__ pscan,
                                                    int* __restrict__ offsets,
                                                    int* __restrict__ cursor,
                                                    float* __restrict__ dis, int n) {
    int b = blockIdx.x, tid = threadIdx.x, lane = tid & 63, wid = tid >> 6;
    int idx = b * 1024 + tid * 4;
    int c0 = 0, c1 = 0, c2 = 0, c3 = 0;
    if (idx + 4 <= n) {
        int4 c = *reinterpret_cast<const int4*>(count + idx);
        c0 = c.x; c1 = c.y; c2 = c.z; c3 = c.w;
    } else {
        if (idx < n) c0 = count[idx];
        if (idx + 1 < n) c1 = count[idx + 1];
        if (idx + 2 < n) c2 = count[idx + 2];
        if (idx + 3 < n) c3 = count[idx + 3];
    }
    int tot = c0 + c1 + c2 + c3;
    int x = tot;
    #pragma unroll
    for (int d = 1; d < 64; d <<= 1) {
        int t = __shfl_up(x, d, 64);
        if (lane >= d) x += t;
    }
    __shared__ int wsum[4];
    if (lane == 63) wsum[wid] = x;
    __syncthreads();
    int wbase = 0;
    for (int w = 0; w < wid; ++w) wbase += wsum[w];
    int base = pscan[b] + wbase + (x - tot);
    int o0 = base, o1 = base + c0, o2 = o1 + c1, o3 = o2 + c2;
    if (idx + 4 <= n) {
        int4 o4 = make_int4(o0, o1, o2, o3);
        *reinterpret_cast<int4*>(offsets + idx) = o4;
        *reinterpret_cast<int4*>(cursor + idx) = o4;
        float4 d4 = make_float4(rsqrtf(c0 + 1.f), rsqrtf(c1 + 1.f),
                                rsqrtf(c2 + 1.f), rsqrtf(c3 + 1.f));
        *reinterpret_cast<float4*>(dis + idx) = d4;
    } else {
        int oo[4] = {o0, o1, o2, o3}; int cc[4] = {c0, c1, c2, c3};
        for (int j = 0; j < 4; ++j) if (idx + j < n) {
            offsets[idx + j] = oo[j]; cursor[idx + j] = oo[j];
            dis[idx + j] = rsqrtf(cc[j] + 1.f);
        }
    }
}

__global__ void fill_kernel(const int* __restrict__ src, const int* __restrict__ dst,
                            int* __restrict__ cursor, int* __restrict__ srcs_sorted, int e) {
    int i = blockIdx.x * blockDim.x + threadIdx.x;
    if (i < e) {
        int d = dst[i];
        int pos = atomicAdd(&cursor[d], 1);
        srcs_sorted[pos] = src[i];
    }
}

// ---------------- prep: x16 = half(x .* dis) ----------------

__global__ __launch_bounds__(256) void prep_x_kernel(const float* __restrict__ x,
                                                     const float* __restrict__ dis,
                                                     Half4* __restrict__ x16, int n) {
    int gid = blockIdx.x * 256 + threadIdx.x;  // one Half4 (4 channels) per thread
    int total = n * 16;
    if (gid >= total) return;
    int node = gid >> 4;
    float4 v = reinterpret_cast<const float4*>(x)[gid];
    float d = dis[node];
    x16[gid] = f4_to_h4(make_float4(v.x * d, v.y * d, v.z * d, v.w * d));
}

// ---------------- aggregate (fp16 payload, f32 accumulate) ----------------
// out[i] = [relu]( dis[i]*( g[i] + sum_edges g[s] ) [+ bias] )   (payloads prescaled by dis)

template<int C, bool RELU, bool BIAS>
__global__ __launch_bounds__(256) void aggregate_h(const __half* __restrict__ g,
                                                   const int* __restrict__ srcs,
                                                   const int* __restrict__ offsets,
                                                   const float* __restrict__ dis,
                                                   const float* __restrict__ bias,
                                                   float* __restrict__ out, int n) {
    int wid = threadIdx.x >> 6, lane = threadIdx.x & 63;
    int i = blockIdx.x * 4 + wid;
    if (i >= n) return;
    float di = dis[i];
    int e0 = offsets[i], e1 = offsets[i + 1];
    int e = e0;

    if constexpr (C == 128) {
        int half = lane >> 5, cl = lane & 31, c = cl * 4;
        const Half4* gc = reinterpret_cast<const Half4*>(g) + cl;  // row stride 32 Half4
        float4 a0 = make_float4(0.f, 0.f, 0.f, 0.f), a1v = a0, a2 = a0, a3 = a0;

        if (half == 0) a0 = h4_to_f4(gc[(size_t)i * 32]);

        for (; e + 8 <= e1; e += 8) {
            int s0 = srcs[e + half], s1 = srcs[e + 2 + half];
            int s2 = srcs[e + 4 + half], s3 = srcs[e + 6 + half];
            float4 l0 = h4_to_f4(gc[(size_t)s0 * 32]);
            float4 l1 = h4_to_f4(gc[(size_t)s1 * 32]);
            float4 l2 = h4_to_f4(gc[(size_t)s2 * 32]);
            float4 l3 = h4_to_f4(gc[(size_t)s3 * 32]);
            a0.x += l0.x; a0.y += l0.y; a0.z += l0.z; a0.w += l0.w;
            a1v.x += l1.x; a1v.y += l1.y; a1v.z += l1.z; a1v.w += l1.w;
            a2.x += l2.x; a2.y += l2.y; a2.z += l2.z; a2.w += l2.w;
            a3.x += l3.x; a3.y += l3.y; a3.z += l3.z; a3.w += l3.w;
        }
        if (e + 4 <= e1) {
            int s0 = srcs[e + half], s1 = srcs[e + 2 + half];
            float4 l0 = h4_to_f4(gc[(size_t)s0 * 32]);
            float4 l1 = h4_to_f4(gc[(size_t)s1 * 32]);
            a0.x += l0.x; a0.y += l0.y; a0.z += l0.z; a0.w += l0.w;
            a1v.x += l1.x; a1v.y += l1.y; a1v.z += l1.z; a1v.w += l1.w;
            e += 4;
        }
        if (e + 2 <= e1) {
            int s0 = srcs[e + half];
            float4 l0 = h4_to_f4(gc[(size_t)s0 * 32]);
            a2.x += l0.x; a2.y += l0.y; a2.z += l0.z; a2.w += l0.w;
            e += 2;
        }
        if (e < e1 && half == 0) {
            int s0 = srcs[e];
            float4 l0 = h4_to_f4(gc[(size_t)s0 * 32]);
            a3.x += l0.x; a3.y += l0.y; a3.z += l0.z; a3.w += l0.w;
        }

        float4 acc = make_float4((a0.x + a1v.x) + (a2.x + a3.x), (a0.y + a1v.y) + (a2.y + a3.y),
                                 (a0.z + a1v.z) + (a2.z + a3.z), (a0.w + a1v.w) + (a2.w + a3.w));
        acc.x += __shfl_xor(acc.x, 32, 64);
        acc.y += __shfl_xor(acc.y, 32, 64);
        acc.z += __shfl_xor(acc.z, 32, 64);
        acc.w += __shfl_xor(acc.w, 32, 64);

        if (half == 0) {
            float4 o = make_float4(di * acc.x, di * acc.y, di * acc.z, di * acc.w);
            if constexpr (BIAS) {
                float4 b = *reinterpret_cast<const float4*>(bias + c);
                o.x += b.x; o.y += b.y; o.z += b.z; o.w += b.w;
            }
            if constexpr (RELU) {
                o.x = fmaxf(o.x, 0.f); o.y = fmaxf(o.y, 0.f);
                o.z = fmaxf(o.z, 0.f); o.w = fmaxf(o.w, 0.f);
            }
            *reinterpret_cast<float4*>(out + (size_t)i * C + c) = o;
        }
    } else {  // C == 64
        int grp = lane >> 4, cl = lane & 15, c = cl * 4;
        const Half4* gc = reinterpret_cast<const Half4*>(g) + cl;  // row stride 16 Half4
        float4 a0 = make_float4(0.f, 0.f, 0.f, 0.f), a1v = a0;

        if (grp == 0) a0 = h4_to_f4(gc[(size_t)i * 16]);

        for (; e + 8 <= e1; e += 8) {
            int s0 = srcs[e + grp], s1 = srcs[e + 4 + grp];
            float4 l0 = h4_to_f4(gc[(size_t)s0 * 16]);
            float4 l1 = h4_to_f4(gc[(size_t)s1 * 16]);
            a0.x += l0.x; a0.y += l0.y; a0.z += l0.z; a0.w += l0.w;
            a1v.x += l1.x; a1v.y += l1.y; a1v.z += l1.z; a1v.w += l1.w;
        }
        if (e + 4 <= e1) {
            int s0 = srcs[e + grp];
            float4 l0 = h4_to_f4(gc[(size_t)s0 * 16]);
            a0.x += l0.x; a0.y += l0.y; a0.z += l0.z; a0.w += l0.w;
            e += 4;
        }
        int rem = e1 - e;  // 0..3
        if (grp < rem) {
            int s0 = srcs[e + grp];
            float4 l0 = h4_to_f4(gc[(size_t)s0 * 16]);
            a1v.x += l0.x; a1v.y += l0.y; a1v.z += l0.z; a1v.w += l0.w;
        }

        float4 acc = make_float4(a0.x + a1v.x, a0.y + a1v.y, a0.z + a1v.z, a0.w + a1v.w);
        #pragma unroll
        for (int d = 16; d <= 32; d <<= 1) {
            acc.x += __shfl_xor(acc.x, d, 64);
            acc.y += __shfl_xor(acc.y, d, 64);
            acc.z += __shfl_xor(acc.z, d, 64);
            acc.w += __shfl_xor(acc.w, d, 64);
        }

        if (grp == 0) {
            float4 o = make_float4(di * acc.x, di * acc.y, di * acc.z, di * acc.w);
            if constexpr (BIAS) {
                float4 b = *reinterpret_cast<const float4*>(bias + c);
                o.x += b.x; o.y += b.y; o.z += b.z; o.w += b.w;
            }
            if constexpr (RELU) {
                o.x = fmaxf(o.x, 0.f); o.y = fmaxf(o.y, 0.f);
                o.z = fmaxf(o.z, 0.f); o.w = fmaxf(o.w, 0.f);
            }
            *reinterpret_cast<float4*>(out + (size_t)i * C + c) = o;
        }
    }
}

// ---------------- GEMM with epilogue ----------------
// EPI 0: out(half) = acc * aux[row]       (aux = dis)
// EPI 1: out(f32)  = relu(acc + aux[col]) (aux = bias)

template<int CIN, int COUT, int RPT, int EPI>
__global__ __launch_bounds__(256) void gemm_ep(const float* __restrict__ in,
                                               const float* __restrict__ W,
                                               const float* __restrict__ aux,
                                               void* __restrict__ outv, int n) {
    constexpr int G = COUT / 4;
    constexpr int TY = 256 / G;
    constexpr int R = TY * RPT;
    __shared__ float wlds[CIN * COUT];
    for (int idx = threadIdx.x * 4; idx < CIN * COUT; idx += 1024)
        *reinterpret_cast<float4*>(&wlds[idx]) = *reinterpret_cast<const float4*>(&W[idx]);
    __syncthreads();

    int tx = threadIdx.x % G;
    int ty = threadIdx.x / G;
    int c0 = tx * 4;
    int rowBase = blockIdx.x * R + ty * RPT;

    int r[RPT];
    #pragma unroll
    for (int j = 0; j < RPT; ++j) r[j] = min(rowBase + j, n - 1);

    float4 acc[RPT];
    #pragma unroll
    for (int j = 0; j < RPT; ++j) acc[j] = make_float4(0.f, 0.f, 0.f, 0.f);

    #pragma unroll 2
    for (int k = 0; k < CIN; k += 4) {
        float4 w0 = *reinterpret_cast<const float4*>(&wlds[(k + 0) * COUT + c0]);
        float4 w1 = *reinterpret_cast<const float4*>(&wlds[(k + 1) * COUT + c0]);
        float4 w2 = *reinterpret_cast<const float4*>(&wlds[(k + 2) * COUT + c0]);
        float4 w3 = *reinterpret_cast<const float4*>(&wlds[(k + 3) * COUT + c0]);
        #pragma unroll
        for (int j = 0; j < RPT; ++j) {
            float4 a = *reinterpret_cast<const float4*>(in + (size_t)r[j] * CIN + k);
            acc[j].x += a.x * w0.x + a.y * w1.x + a.z * w2.x + a.w * w3.x;
            acc[j].y += a.x * w0.y + a.y * w1.y + a.z * w2.y + a.w * w3.y;
            acc[j].z += a.x * w0.z + a.y * w1.z + a.z * w2.z + a.w * w3.z;
            acc[j].w += a.x * w0.w + a.y * w1.w + a.z * w2.w + a.w * w3.w;
        }
    }

    if constexpr (EPI == 1) {
        float* out = (float*)outv;
        float4 b = *reinterpret_cast<const float4*>(aux + c0);
        #pragma unroll
        for (int j = 0; j < RPT; ++j) {
            if (rowBase + j < n) {
                float4 o = make_float4(fmaxf(acc[j].x + b.x, 0.f), fmaxf(acc[j].y + b.y, 0.f),
                                       fmaxf(acc[j].z + b.z, 0.f), fmaxf(acc[j].w + b.w, 0.f));
                *reinterpret_cast<float4*>(out + (size_t)r[j] * COUT + c0) = o;
            }
        }
    } else {
        Half4* out = (Half4*)outv;
        #pragma unroll
        for (int j = 0; j < RPT; ++j) {
            if (rowBase + j < n) {
                float d = aux[r[j]];
                out[(size_t)r[j] * (COUT / 4) + tx] =
                    f4_to_h4(make_float4(acc[j].x * d, acc[j].y * d, acc[j].z * d, acc[j].w * d));
            }
        }
    }
}

// ---------------- launch ----------------

extern "C" void kernel_launch(void* const* d_in, const int* in_sizes, int n_in,
                              void* d_out, int out_size, void* d_ws, size_t ws_size,
                              hipStream_t stream) {
    const float* x  = (const float*)d_in[0];
    const int*   ei = (const int*)d_in[1];
    const float* W1 = (const float*)d_in[2];
    const float* b1 = (const float*)d_in[3];
    const float* W2 = (const float*)d_in[4];
    const float* b2 = (const float*)d_in[5];
    const float* W3 = (const float*)d_in[6];
    const float* b3 = (const float*)d_in[7];

    const int n = in_sizes[0] / 64;   // 50000
    const int e = in_sizes[1] / 2;    // 800000
    const int* src = ei;
    const int* dst = ei + e;

    // workspace layout (4-byte units)
    int*   ws_i = (int*)d_ws;
    float* ws_f = (float*)d_ws;
    size_t o = 0;
    int* count   = ws_i + o; o += n;
    int* offsets = ws_i + o; o += n + 8;
    int* cursor  = ws_i + o; o += n;
    int* srcs    = ws_i + o; o += e;
    int* partial = ws_i + o; o += 256;
    int* pscan   = ws_i + o; o += 256;
    float* dis   = ws_f + o; o += n;
    o = (o + 3) & ~(size_t)3;
    float* R1 = ws_f + o; o += (size_t)n * 128;   // a1 (64w), then h2 (128w)
    float* R2 = ws_f + o; o += (size_t)n * 128;   // h1 (128w), then g3 (64w half)

    // d_out doubles as scratch: x16 (half 64w), then g2 (half 128w), then final out
    Half4*  x16 = (Half4*)d_out;
    __half* g2  = (__half*)d_out;
    float*  a1  = R1;
    float*  h1  = R2;
    float*  h2  = R1;
    __half* g3  = (__half*)R2;
    float*  out = (float*)d_out;

    const int B = 256;
    const int P = (n + 1023) / 1024;
    hipMemsetAsync(count, 0, (size_t)n * sizeof(int), stream);
    count_kernel<<<(e + B - 1) / B, B, 0, stream>>>(dst, count, e);
    partial_kernel<<<P, B, 0, stream>>>(count, partial, n);
    scan_partials_kernel<<<1, 64, 0, stream>>>(partial, pscan, offsets, n, P);
    apply_kernel<<<P, B, 0, stream>>>(count, pscan, offsets, cursor, dis, n);
    fill_kernel<<<(e + B - 1) / B, B, 0, stream>>>(src, dst, cursor, srcs, e);
    prep_x_kernel<<<(n * 16 + B - 1) / B, B, 0, stream>>>(x, dis, x16, n);

    dim3 agrid((n + 3) / 4);
    dim3 ggrid((n + 63) / 64);

    // L1: a1 = dis*agg(x16); h1 = relu(a1@W1+b1)
    aggregate_h<64, false, false><<<agrid, 256, 0, stream>>>((const __half*)x16, srcs, offsets, dis, nullptr, a1, n);
    gemm_ep<64, 128, 8, 1><<<ggrid, 256, 0, stream>>>(a1, W1, b1, h1, n);
    // L2: g2 = half((h1@W2)*dis); h2 = relu(dis*agg(g2)+b2)
    gemm_ep<128, 128, 8, 0><<<ggrid, 256, 0, stream>>>(h1, W2, dis, g2, n);
    aggregate_h<128, true, true><<<agrid, 256, 0, stream>>>(g2, srcs, offsets, dis, b2, h2, n);
    // L3: g3 = half((h2@W3)*dis); out = dis*agg(g3)+b3
    gemm_ep<128, 64, 4, 0><<<ggrid, 256, 0, stream>>>(h2, W3, dis, g3, n);
    aggregate_h<64, false, true><<<agrid, 256, 0, stream>>>(g3, srcs, offsets, dis, b3, out, n);
}

// Round 7
// 234.902 us; speedup vs baseline: 1.7197x; 1.2317x over previous
//
#include <hip/hip_runtime.h>
#include <hip/hip_fp16.h>

// GCN 3-layer, fp16 message payloads (f32 accumulate):
// prep: x16 = half(x .* dis)
// L1: a1 = dis.*agg(x16)            ; h1 = relu(a1@W1+b1)        [agg64h + gemm EPI1]
// L2: g2 = half((h1@W2).*dis)       ; h2 = relu(dis.*agg(g2)+b2) [gemm EPI0 + agg128h]
// L3: g3 = half((h2@W3).*dis)       ; out = dis.*agg(g3)+b3      [gemm EPI0 + agg64h]
// dis[i] = rsqrt(1 + indegree[i])
// CSR build: two-level counting sort (128-node buckets) to keep scatters XCD-local.

struct alignas(8) Half4 { __half2 lo, hi; };

__device__ inline float4 h4_to_f4(Half4 h) {
    float2 a = __half22float2(h.lo), b = __half22float2(h.hi);
    return make_float4(a.x, a.y, b.x, b.y);
}
__device__ inline Half4 f4_to_h4(float4 v) {
    Half4 h; h.lo = __floats2half2_rn(v.x, v.y); h.hi = __floats2half2_rn(v.z, v.w); return h;
}

#define MAXNB 512   // buckets of 128 nodes; covers n <= 65536

// ---------------- R1: bucket histogram ----------------

__global__ __launch_bounds__(256) void bucket_count(const int* __restrict__ dst,
                                                    int* __restrict__ bcnt, int e, int nb) {
    __shared__ int h[MAXNB];
    int tid = threadIdx.x;
    for (int i = tid; i < nb; i += 256) h[i] = 0;
    __syncthreads();
    for (int i = blockIdx.x * 256 + tid; i < e; i += gridDim.x * 256)
        atomicAdd(&h[dst[i] >> 7], 1);
    __syncthreads();
    for (int i = tid; i < nb; i += 256) {
        int c = h[i];
        if (c) atomicAdd(&bcnt[i], c);
    }
}

// ---------------- R2: single-wave exclusive scan of bucket counts ----------------

__global__ void scan_buckets(const int* __restrict__ bcnt, int* __restrict__ bbase,
                             int* __restrict__ bcursor, int nb) {
    int lane = threadIdx.x;  // 64 threads
    int running = 0;
    for (int base = 0; base < nb; base += 64) {
        int idx = base + lane;
        int v = (idx < nb) ? bcnt[idx] : 0;
        int x = v;
        #pragma unroll
        for (int d = 1; d < 64; d <<= 1) {
            int t = __shfl_up(x, d, 64);
            if (lane >= d) x += t;
        }
        if (idx < nb) { bbase[idx] = running + x - v; bcursor[idx] = running + x - v; }
        running += __shfl(x, 63, 64);
    }
    if (lane == 0) bbase[nb] = running;
}

// ---------------- R3: bin edges into bucket segments (bulk-reserved, burst writes) ----------

#define R3_CHUNK 4096

__global__ __launch_bounds__(256) void bin_edges(const int* __restrict__ src,
                                                 const int* __restrict__ dst,
                                                 int* __restrict__ bcursor,
                                                 int2* __restrict__ binned, int e, int nb) {
    __shared__ int h[MAXNB];
    __shared__ int gp[MAXNB];
    int tid = threadIdx.x;
    for (int i = tid; i < nb; i += 256) h[i] = 0;
    __syncthreads();
    int lo = blockIdx.x * R3_CHUNK, hi = min(lo + R3_CHUNK, e);
    for (int i = lo + tid; i < hi; i += 256) atomicAdd(&h[dst[i] >> 7], 1);
    __syncthreads();
    for (int b = tid; b < nb; b += 256) {
        int c = h[b];
        if (c) gp[b] = atomicAdd(&bcursor[b], c);
        h[b] = 0;  // reuse as local cursor
    }
    __syncthreads();
    for (int i = lo + tid; i < hi; i += 256) {
        int d = dst[i];
        int b = d >> 7;
        int p = atomicAdd(&h[b], 1);
        binned[gp[b] + p] = make_int2(src[i], d);
    }
}

// ---------------- R4: per-bucket finalize: node counts, offsets, dis, local scatter ------

__global__ __launch_bounds__(128) void finalize_csr(const int2* __restrict__ binned,
                                                    const int* __restrict__ bbase,
                                                    int* __restrict__ offsets,
                                                    int* __restrict__ srcs,
                                                    float* __restrict__ dis,
                                                    int n, int nb) {
    int b = blockIdx.x;
    int tid = threadIdx.x;  // 128 threads, one node each
    int nb0 = b << 7;
    int segLo = bbase[b], segHi = bbase[b + 1];

    __shared__ int cnt[128];
    __shared__ int cur[128];
    __shared__ int wtot;
    cnt[tid] = 0;
    __syncthreads();
    for (int i = segLo + tid; i < segHi; i += 128)
        atomicAdd(&cnt[binned[i].y & 127], 1);
    __syncthreads();

    int c = cnt[tid];
    int lane = tid & 63, w = tid >> 6;
    int x = c;
    #pragma unroll
    for (int d = 1; d < 64; d <<= 1) {
        int t = __shfl_up(x, d, 64);
        if (lane >= d) x += t;
    }
    if (w == 0 && lane == 63) wtot = x;
    __syncthreads();
    int excl = x - c + (w ? wtot : 0);

    int node = nb0 + tid;
    if (node < n) {
        offsets[node] = segLo + excl;
        dis[node] = rsqrtf((float)(c + 1));
    }
    if (b == nb - 1 && tid == 0) offsets[n] = segHi;
    cur[tid] = excl;
    __syncthreads();

    for (int i = segLo + tid; i < segHi; i += 128) {
        int2 v = binned[i];
        int ln = v.y & 127;
        int p = atomicAdd(&cur[ln], 1);
        srcs[segLo + p] = v.x;
    }
}

// ---------------- prep: x16 = half(x .* dis) ----------------

__global__ __launch_bounds__(256) void prep_x_kernel(const float* __restrict__ x,
                                                     const float* __restrict__ dis,
                                                     Half4* __restrict__ x16, int n) {
    int gid = blockIdx.x * 256 + threadIdx.x;  // one Half4 (4 channels) per thread
    int total = n * 16;
    if (gid >= total) return;
    int node = gid >> 4;
    float4 v = reinterpret_cast<const float4*>(x)[gid];
    float d = dis[node];
    x16[gid] = f4_to_h4(make_float4(v.x * d, v.y * d, v.z * d, v.w * d));
}

// ---------------- aggregate (fp16 payload, f32 accumulate) ----------------
// out[i] = [relu]( dis[i]*( g[i] + sum_edges g[s] ) [+ bias] )   (payloads prescaled)

template<int C, bool RELU, bool BIAS>
__global__ __launch_bounds__(256) void aggregate_h(const __half* __restrict__ g,
                                                   const int* __restrict__ srcs,
                                                   const int* __restrict__ offsets,
                                                   const float* __restrict__ dis,
                                                   const float* __restrict__ bias,
                                                   float* __restrict__ out, int n) {
    int wid = threadIdx.x >> 6, lane = threadIdx.x & 63;
    int i = blockIdx.x * 4 + wid;
    if (i >= n) return;
    float di = dis[i];
    int e0 = offsets[i], e1 = offsets[i + 1];
    int e = e0;

    if constexpr (C == 128) {
        int half = lane >> 5, cl = lane & 31, c = cl * 4;
        const Half4* gc = reinterpret_cast<const Half4*>(g) + cl;  // row stride 32 Half4
        float4 a0 = make_float4(0.f, 0.f, 0.f, 0.f), a1v = a0, a2 = a0, a3 = a0;

        if (half == 0) a0 = h4_to_f4(gc[(size_t)i * 32]);

        for (; e + 8 <= e1; e += 8) {
            int s0 = srcs[e + half], s1 = srcs[e + 2 + half];
            int s2 = srcs[e + 4 + half], s3 = srcs[e + 6 + half];
            float4 l0 = h4_to_f4(gc[(size_t)s0 * 32]);
            float4 l1 = h4_to_f4(gc[(size_t)s1 * 32]);
            float4 l2 = h4_to_f4(gc[(size_t)s2 * 32]);
            float4 l3 = h4_to_f4(gc[(size_t)s3 * 32]);
            a0.x += l0.x; a0.y += l0.y; a0.z += l0.z; a0.w += l0.w;
            a1v.x += l1.x; a1v.y += l1.y; a1v.z += l1.z; a1v.w += l1.w;
            a2.x += l2.x; a2.y += l2.y; a2.z += l2.z; a2.w += l2.w;
            a3.x += l3.x; a3.y += l3.y; a3.z += l3.z; a3.w += l3.w;
        }
        if (e + 4 <= e1) {
            int s0 = srcs[e + half], s1 = srcs[e + 2 + half];
            float4 l0 = h4_to_f4(gc[(size_t)s0 * 32]);
            float4 l1 = h4_to_f4(gc[(size_t)s1 * 32]);
            a0.x += l0.x; a0.y += l0.y; a0.z += l0.z; a0.w += l0.w;
            a1v.x += l1.x; a1v.y += l1.y; a1v.z += l1.z; a1v.w += l1.w;
            e += 4;
        }
        if (e + 2 <= e1) {
            int s0 = srcs[e + half];
            float4 l0 = h4_to_f4(gc[(size_t)s0 * 32]);
            a2.x += l0.x; a2.y += l0.y; a2.z += l0.z; a2.w += l0.w;
            e += 2;
        }
        if (e < e1 && half == 0) {
            int s0 = srcs[e];
            float4 l0 = h4_to_f4(gc[(size_t)s0 * 32]);
            a3.x += l0.x; a3.y += l0.y; a3.z += l0.z; a3.w += l0.w;
        }

        float4 acc = make_float4((a0.x + a1v.x) + (a2.x + a3.x), (a0.y + a1v.y) + (a2.y + a3.y),
                                 (a0.z + a1v.z) + (a2.z + a3.z), (a0.w + a1v.w) + (a2.w + a3.w));
        acc.x += __shfl_xor(acc.x, 32, 64);
        acc.y += __shfl_xor(acc.y, 32, 64);
        acc.z += __shfl_xor(acc.z, 32, 64);
        acc.w += __shfl_xor(acc.w, 32, 64);

        if (half == 0) {
            float4 o = make_float4(di * acc.x, di * acc.y, di * acc.z, di * acc.w);
            if constexpr (BIAS) {
                float4 b = *reinterpret_cast<const float4*>(bias + c);
                o.x += b.x; o.y += b.y; o.z += b.z; o.w += b.w;
            }
            if constexpr (RELU) {
                o.x = fmaxf(o.x, 0.f); o.y = fmaxf(o.y, 0.f);
                o.z = fmaxf(o.z, 0.f); o.w = fmaxf(o.w, 0.f);
            }
            *reinterpret_cast<float4*>(out + (size_t)i * C + c) = o;
        }
    } else {  // C == 64
        int grp = lane >> 4, cl = lane & 15, c = cl * 4;
        const Half4* gc = reinterpret_cast<const Half4*>(g) + cl;  // row stride 16 Half4
        float4 a0 = make_float4(0.f, 0.f, 0.f, 0.f), a1v = a0;

        if (grp == 0) a0 = h4_to_f4(gc[(size_t)i * 16]);

        for (; e + 8 <= e1; e += 8) {
            int s0 = srcs[e + grp], s1 = srcs[e + 4 + grp];
            float4 l0 = h4_to_f4(gc[(size_t)s0 * 16]);
            float4 l1 = h4_to_f4(gc[(size_t)s1 * 16]);
            a0.x += l0.x; a0.y += l0.y; a0.z += l0.z; a0.w += l0.w;
            a1v.x += l1.x; a1v.y += l1.y; a1v.z += l1.z; a1v.w += l1.w;
        }
        if (e + 4 <= e1) {
            int s0 = srcs[e + grp];
            float4 l0 = h4_to_f4(gc[(size_t)s0 * 16]);
            a0.x += l0.x; a0.y += l0.y; a0.z += l0.z; a0.w += l0.w;
            e += 4;
        }
        int rem = e1 - e;  // 0..3
        if (grp < rem) {
            int s0 = srcs[e + grp];
            float4 l0 = h4_to_f4(gc[(size_t)s0 * 16]);
            a1v.x += l0.x; a1v.y += l0.y; a1v.z += l0.z; a1v.w += l0.w;
        }

        float4 acc = make_float4(a0.x + a1v.x, a0.y + a1v.y, a0.z + a1v.z, a0.w + a1v.w);
        #pragma unroll
        for (int d = 16; d <= 32; d <<= 1) {
            acc.x += __shfl_xor(acc.x, d, 64);
            acc.y += __shfl_xor(acc.y, d, 64);
            acc.z += __shfl_xor(acc.z, d, 64);
            acc.w += __shfl_xor(acc.w, d, 64);
        }

        if (grp == 0) {
            float4 o = make_float4(di * acc.x, di * acc.y, di * acc.z, di * acc.w);
            if constexpr (BIAS) {
                float4 b = *reinterpret_cast<const float4*>(bias + c);
                o.x += b.x; o.y += b.y; o.z += b.z; o.w += b.w;
            }
            if constexpr (RELU) {
                o.x = fmaxf(o.x, 0.f); o.y = fmaxf(o.y, 0.f);
                o.z = fmaxf(o.z, 0.f); o.w = fmaxf(o.w, 0.f);
            }
            *reinterpret_cast<float4*>(out + (size_t)i * C + c) = o;
        }
    }
}

// ---------------- GEMM with epilogue ----------------
// EPI 0: out(half) = acc * aux[row]       (aux = dis)
// EPI 1: out(f32)  = relu(acc + aux[col]) (aux = bias)

template<int CIN, int COUT, int RPT, int EPI>
__global__ __launch_bounds__(256) void gemm_ep(const float* __restrict__ in,
                                               const float* __restrict__ W,
                                               const float* __restrict__ aux,
                                               void* __restrict__ outv, int n) {
    constexpr int G = COUT / 4;
    constexpr int TY = 256 / G;
    constexpr int R = TY * RPT;
    __shared__ float wlds[CIN * COUT];
    for (int idx = threadIdx.x * 4; idx < CIN * COUT; idx += 1024)
        *reinterpret_cast<float4*>(&wlds[idx]) = *reinterpret_cast<const float4*>(&W[idx]);
    __syncthreads();

    int tx = threadIdx.x % G;
    int ty = threadIdx.x / G;
    int c0 = tx * 4;
    int rowBase = blockIdx.x * R + ty * RPT;

    int r[RPT];
    #pragma unroll
    for (int j = 0; j < RPT; ++j) r[j] = min(rowBase + j, n - 1);

    float4 acc[RPT];
    #pragma unroll
    for (int j = 0; j < RPT; ++j) acc[j] = make_float4(0.f, 0.f, 0.f, 0.f);

    #pragma unroll 2
    for (int k = 0; k < CIN; k += 4) {
        float4 w0 = *reinterpret_cast<const float4*>(&wlds[(k + 0) * COUT + c0]);
        float4 w1 = *reinterpret_cast<const float4*>(&wlds[(k + 1) * COUT + c0]);
        float4 w2 = *reinterpret_cast<const float4*>(&wlds[(k + 2) * COUT + c0]);
        float4 w3 = *reinterpret_cast<const float4*>(&wlds[(k + 3) * COUT + c0]);
        #pragma unroll
        for (int j = 0; j < RPT; ++j) {
            float4 a = *reinterpret_cast<const float4*>(in + (size_t)r[j] * CIN + k);
            acc[j].x += a.x * w0.x + a.y * w1.x + a.z * w2.x + a.w * w3.x;
            acc[j].y += a.x * w0.y + a.y * w1.y + a.z * w2.y + a.w * w3.y;
            acc[j].z += a.x * w0.z + a.y * w1.z + a.z * w2.z + a.w * w3.z;
            acc[j].w += a.x * w0.w + a.y * w1.w + a.z * w2.w + a.w * w3.w;
        }
    }

    if constexpr (EPI == 1) {
        float* out = (float*)outv;
        float4 b = *reinterpret_cast<const float4*>(aux + c0);
        #pragma unroll
        for (int j = 0; j < RPT; ++j) {
            if (rowBase + j < n) {
                float4 o = make_float4(fmaxf(acc[j].x + b.x, 0.f), fmaxf(acc[j].y + b.y, 0.f),
                                       fmaxf(acc[j].z + b.z, 0.f), fmaxf(acc[j].w + b.w, 0.f));
                *reinterpret_cast<float4*>(out + (size_t)r[j] * COUT + c0) = o;
            }
        }
    } else {
        Half4* out = (Half4*)outv;
        #pragma unroll
        for (int j = 0; j < RPT; ++j) {
            if (rowBase + j < n) {
                float d = aux[r[j]];
                out[(size_t)r[j] * (COUT / 4) + tx] =
                    f4_to_h4(make_float4(acc[j].x * d, acc[j].y * d, acc[j].z * d, acc[j].w * d));
            }
        }
    }
}

// ---------------- launch ----------------

extern "C" void kernel_launch(void* const* d_in, const int* in_sizes, int n_in,
                              void* d_out, int out_size, void* d_ws, size_t ws_size,
                              hipStream_t stream) {
    const float* x  = (const float*)d_in[0];
    const int*   ei = (const int*)d_in[1];
    const float* W1 = (const float*)d_in[2];
    const float* b1 = (const float*)d_in[3];
    const float* W2 = (const float*)d_in[4];
    const float* b2 = (const float*)d_in[5];
    const float* W3 = (const float*)d_in[6];
    const float* b3 = (const float*)d_in[7];

    const int n = in_sizes[0] / 64;   // 50000
    const int e = in_sizes[1] / 2;    // 800000
    const int* src = ei;
    const int* dst = ei + e;
    const int nb = (n + 127) >> 7;    // 128-node buckets

    // workspace layout (4-byte units; keep 8B alignment for int2 binned)
    int*   ws_i = (int*)d_ws;
    float* ws_f = (float*)d_ws;
    size_t o = 0;
    int* bcnt    = ws_i + o; o += MAXNB;
    int* bbase   = ws_i + o; o += MAXNB + 2;
    int* bcursor = ws_i + o; o += MAXNB;
    int* offsets = ws_i + o; o += n + 8;
    int* srcs    = ws_i + o; o += e;
    float* dis   = ws_f + o; o += n;
    o = (o + 1) & ~(size_t)1;
    int2* binned = (int2*)(ws_i + o); o += (size_t)e * 2;
    o = (o + 3) & ~(size_t)3;
    float* R1 = ws_f + o; o += (size_t)n * 128;   // a1 (64w f32), then h2 (128w f32)
    float* R2 = ws_f + o; o += (size_t)n * 128;   // h1 (128w f32), then g3 (64w half)

    // d_out doubles as scratch: x16 (half 64w), then g2 (half 128w), then final out
    Half4*  x16 = (Half4*)d_out;
    __half* g2  = (__half*)d_out;
    float*  a1  = R1;
    float*  h1  = R2;
    float*  h2  = R1;
    __half* g3  = (__half*)R2;
    float*  out = (float*)d_out;

    const int B = 256;
    // CSR build (two-level counting sort)
    hipMemsetAsync(bcnt, 0, MAXNB * sizeof(int), stream);
    bucket_count<<<256, B, 0, stream>>>(dst, bcnt, e, nb);
    scan_buckets<<<1, 64, 0, stream>>>(bcnt, bbase, bcursor, nb);
    bin_edges<<<(e + R3_CHUNK - 1) / R3_CHUNK, B, 0, stream>>>(src, dst, bcursor, binned, e, nb);
    finalize_csr<<<nb, 128, 0, stream>>>(binned, bbase, offsets, srcs, dis, n, nb);
    prep_x_kernel<<<(n * 16 + B - 1) / B, B, 0, stream>>>(x, dis, x16, n);

    dim3 agrid((n + 3) / 4);
    dim3 ggrid((n + 63) / 64);

    // L1: a1 = dis*agg(x16); h1 = relu(a1@W1+b1)
    aggregate_h<64, false, false><<<agrid, 256, 0, stream>>>((const __half*)x16, srcs, offsets, dis, nullptr, a1, n);
    gemm_ep<64, 128, 8, 1><<<ggrid, 256, 0, stream>>>(a1, W1, b1, h1, n);
    // L2: g2 = half((h1@W2)*dis); h2 = relu(dis*agg(g2)+b2)
    gemm_ep<128, 128, 8, 0><<<ggrid, 256, 0, stream>>>(h1, W2, dis, g2, n);
    aggregate_h<128, true, true><<<agrid, 256, 0, stream>>>(g2, srcs, offsets, dis, b2, h2, n);
    // L3: g3 = half((h2@W3)*dis); out = dis*agg(g3)+b3
    gemm_ep<128, 64, 4, 0><<<ggrid, 256, 0, stream>>>(h2, W3, dis, g3, n);
    aggregate_h<64, false, true><<<agrid, 256, 0, stream>>>(g3, srcs, offsets, dis, b3, out, n);
}

// Round 8
// 178.672 us; speedup vs baseline: 2.2610x; 1.3147x over previous
//
#include <hip/hip_runtime.h>
#include <hip/hip_fp16.h>

// GCN 3-layer, fp16 payloads + MFMA GEMMs (f32 accumulate):
// prep: x16 = half(x .* dis)
// L1: a1h = half(dis.*agg(x16)) ; h1h = half(relu(a1@W1+b1))   [agg64h + mfma_gemm EPI1]
// L2: g2 = half((h1@W2).*dis)   ; h2h = half(relu(dis.*agg(g2)+b2)) [mfma EPI0 + agg128h]
// L3: g3 = half((h2@W3).*dis)   ; out = dis.*agg(g3)+b3        [mfma EPI0 + agg64h f32]
// dis[i] = rsqrt(1 + indegree[i])
// CSR build: two-level counting sort (128-node buckets) keeps scatters XCD-local.
// MFMA fragment layout (16x16x32 f16): A/B lane l elem j -> k=(l>>4)*4+(j&3)+16*(j>>2),
// A: m=l&15, B: n=l&15. C/D: col=lane&15, row=(lane>>4)*4+reg.

typedef _Float16 h8 __attribute__((ext_vector_type(8)));
typedef float f32x4 __attribute__((ext_vector_type(4)));

struct alignas(8) Half4 { __half2 lo, hi; };

__device__ inline float4 h4_to_f4(Half4 h) {
    float2 a = __half22float2(h.lo), b = __half22float2(h.hi);
    return make_float4(a.x, a.y, b.x, b.y);
}
__device__ inline Half4 f4_to_h4(float4 v) {
    Half4 h; h.lo = __floats2half2_rn(v.x, v.y); h.hi = __floats2half2_rn(v.z, v.w); return h;
}

#define MAXNB 512   // buckets of 128 nodes; covers n <= 65536

// ---------------- R1: bucket histogram ----------------

__global__ __launch_bounds__(256) void bucket_count(const int* __restrict__ dst,
                                                    int* __restrict__ bcnt, int e, int nb) {
    __shared__ int h[MAXNB];
    int tid = threadIdx.x;
    for (int i = tid; i < nb; i += 256) h[i] = 0;
    __syncthreads();
    for (int i = blockIdx.x * 256 + tid; i < e; i += gridDim.x * 256)
        atomicAdd(&h[dst[i] >> 7], 1);
    __syncthreads();
    for (int i = tid; i < nb; i += 256) {
        int c = h[i];
        if (c) atomicAdd(&bcnt[i], c);
    }
}

// ---------------- R2: single-wave exclusive scan of bucket counts ----------------

__global__ void scan_buckets(const int* __restrict__ bcnt, int* __restrict__ bbase,
                             int* __restrict__ bcursor, int nb) {
    int lane = threadIdx.x;  // 64 threads
    int running = 0;
    for (int base = 0; base < nb; base += 64) {
        int idx = base + lane;
        int v = (idx < nb) ? bcnt[idx] : 0;
        int x = v;
        #pragma unroll
        for (int d = 1; d < 64; d <<= 1) {
            int t = __shfl_up(x, d, 64);
            if (lane >= d) x += t;
        }
        if (idx < nb) { bbase[idx] = running + x - v; bcursor[idx] = running + x - v; }
        running += __shfl(x, 63, 64);
    }
    if (lane == 0) bbase[nb] = running;
}

// ---------------- R3: bin edges into bucket segments ----------------

#define R3_CHUNK 4096

__global__ __launch_bounds__(256) void bin_edges(const int* __restrict__ src,
                                                 const int* __restrict__ dst,
                                                 int* __restrict__ bcursor,
                                                 int2* __restrict__ binned, int e, int nb) {
    __shared__ int h[MAXNB];
    __shared__ int gp[MAXNB];
    int tid = threadIdx.x;
    for (int i = tid; i < nb; i += 256) h[i] = 0;
    __syncthreads();
    int lo = blockIdx.x * R3_CHUNK, hi = min(lo + R3_CHUNK, e);
    for (int i = lo + tid; i < hi; i += 256) atomicAdd(&h[dst[i] >> 7], 1);
    __syncthreads();
    for (int b = tid; b < nb; b += 256) {
        int c = h[b];
        if (c) gp[b] = atomicAdd(&bcursor[b], c);
        h[b] = 0;  // reuse as local cursor
    }
    __syncthreads();
    for (int i = lo + tid; i < hi; i += 256) {
        int d = dst[i];
        int b = d >> 7;
        int p = atomicAdd(&h[b], 1);
        binned[gp[b] + p] = make_int2(src[i], d);
    }
}

// ---------------- R4: per-bucket finalize ----------------

__global__ __launch_bounds__(128) void finalize_csr(const int2* __restrict__ binned,
                                                    const int* __restrict__ bbase,
                                                    int* __restrict__ offsets,
                                                    int* __restrict__ srcs,
                                                    float* __restrict__ dis,
                                                    int n, int nb) {
    int b = blockIdx.x;
    int tid = threadIdx.x;  // 128 threads, one node each
    int nb0 = b << 7;
    int segLo = bbase[b], segHi = bbase[b + 1];

    __shared__ int cnt[128];
    __shared__ int cur[128];
    __shared__ int wtot;
    cnt[tid] = 0;
    __syncthreads();
    for (int i = segLo + tid; i < segHi; i += 128)
        atomicAdd(&cnt[binned[i].y & 127], 1);
    __syncthreads();

    int c = cnt[tid];
    int lane = tid & 63, w = tid >> 6;
    int x = c;
    #pragma unroll
    for (int d = 1; d < 64; d <<= 1) {
        int t = __shfl_up(x, d, 64);
        if (lane >= d) x += t;
    }
    if (w == 0 && lane == 63) wtot = x;
    __syncthreads();
    int excl = x - c + (w ? wtot : 0);

    int node = nb0 + tid;
    if (node < n) {
        offsets[node] = segLo + excl;
        dis[node] = rsqrtf((float)(c + 1));
    }
    if (b == nb - 1 && tid == 0) offsets[n] = segHi;
    cur[tid] = excl;
    __syncthreads();

    for (int i = segLo + tid; i < segHi; i += 128) {
        int2 v = binned[i];
        int ln = v.y & 127;
        int p = atomicAdd(&cur[ln], 1);
        srcs[segLo + p] = v.x;
    }
}

// ---------------- prep: x16 = half(x .* dis) ----------------

__global__ __launch_bounds__(256) void prep_x_kernel(const float* __restrict__ x,
                                                     const float* __restrict__ dis,
                                                     Half4* __restrict__ x16, int n) {
    int gid = blockIdx.x * 256 + threadIdx.x;
    int total = n * 16;
    if (gid >= total) return;
    int node = gid >> 4;
    float4 v = reinterpret_cast<const float4*>(x)[gid];
    float d = dis[node];
    x16[gid] = f4_to_h4(make_float4(v.x * d, v.y * d, v.z * d, v.w * d));
}

// ---------------- aggregate (fp16 payload, f32 accumulate) ----------------
// out[i] = [relu]( dis[i]*( g[i] + sum_edges g[s] ) [+ bias] ), payloads prescaled.
// OUTH: write half output (Half4) instead of float4.

template<int C, bool RELU, bool BIAS, bool OUTH>
__global__ __launch_bounds__(256) void aggregate_h(const __half* __restrict__ g,
                                                   const int* __restrict__ srcs,
                                                   const int* __restrict__ offsets,
                                                   const float* __restrict__ dis,
                                                   const float* __restrict__ bias,
                                                   void* __restrict__ outv, int n) {
    int wid = threadIdx.x >> 6, lane = threadIdx.x & 63;
    int i = blockIdx.x * 4 + wid;
    if (i >= n) return;
    float di = dis[i];
    int e0 = offsets[i], e1 = offsets[i + 1];
    int e = e0;

    if constexpr (C == 128) {
        int half_ = lane >> 5, cl = lane & 31, c = cl * 4;
        const Half4* gc = reinterpret_cast<const Half4*>(g) + cl;  // row stride 32 Half4
        float4 a0 = make_float4(0.f, 0.f, 0.f, 0.f), a1v = a0, a2 = a0, a3 = a0;

        if (half_ == 0) a0 = h4_to_f4(gc[(size_t)i * 32]);

        for (; e + 8 <= e1; e += 8) {
            int s0 = srcs[e + half_], s1 = srcs[e + 2 + half_];
            int s2 = srcs[e + 4 + half_], s3 = srcs[e + 6 + half_];
            float4 l0 = h4_to_f4(gc[(size_t)s0 * 32]);
            float4 l1 = h4_to_f4(gc[(size_t)s1 * 32]);
            float4 l2 = h4_to_f4(gc[(size_t)s2 * 32]);
            float4 l3 = h4_to_f4(gc[(size_t)s3 * 32]);
            a0.x += l0.x; a0.y += l0.y; a0.z += l0.z; a0.w += l0.w;
            a1v.x += l1.x; a1v.y += l1.y; a1v.z += l1.z; a1v.w += l1.w;
            a2.x += l2.x; a2.y += l2.y; a2.z += l2.z; a2.w += l2.w;
            a3.x += l3.x; a3.y += l3.y; a3.z += l3.z; a3.w += l3.w;
        }
        if (e + 4 <= e1) {
            int s0 = srcs[e + half_], s1 = srcs[e + 2 + half_];
            float4 l0 = h4_to_f4(gc[(size_t)s0 * 32]);
            float4 l1 = h4_to_f4(gc[(size_t)s1 * 32]);
            a0.x += l0.x; a0.y += l0.y; a0.z += l0.z; a0.w += l0.w;
            a1v.x += l1.x; a1v.y += l1.y; a1v.z += l1.z; a1v.w += l1.w;
            e += 4;
        }
        if (e + 2 <= e1) {
            int s0 = srcs[e + half_];
            float4 l0 = h4_to_f4(gc[(size_t)s0 * 32]);
            a2.x += l0.x; a2.y += l0.y; a2.z += l0.z; a2.w += l0.w;
            e += 2;
        }
        if (e < e1 && half_ == 0) {
            int s0 = srcs[e];
            float4 l0 = h4_to_f4(gc[(size_t)s0 * 32]);
            a3.x += l0.x; a3.y += l0.y; a3.z += l0.z; a3.w += l0.w;
        }

        float4 acc = make_float4((a0.x + a1v.x) + (a2.x + a3.x), (a0.y + a1v.y) + (a2.y + a3.y),
                                 (a0.z + a1v.z) + (a2.z + a3.z), (a0.w + a1v.w) + (a2.w + a3.w));
        acc.x += __shfl_xor(acc.x, 32, 64);
        acc.y += __shfl_xor(acc.y, 32, 64);
        acc.z += __shfl_xor(acc.z, 32, 64);
        acc.w += __shfl_xor(acc.w, 32, 64);

        if (half_ == 0) {
            float4 o = make_float4(di * acc.x, di * acc.y, di * acc.z, di * acc.w);
            if constexpr (BIAS) {
                float4 b = *reinterpret_cast<const float4*>(bias + c);
                o.x += b.x; o.y += b.y; o.z += b.z; o.w += b.w;
            }
            if constexpr (RELU) {
                o.x = fmaxf(o.x, 0.f); o.y = fmaxf(o.y, 0.f);
                o.z = fmaxf(o.z, 0.f); o.w = fmaxf(o.w, 0.f);
            }
            if constexpr (OUTH)
                *reinterpret_cast<Half4*>((__half*)outv + (size_t)i * C + c) = f4_to_h4(o);
            else
                *reinterpret_cast<float4*>((float*)outv + (size_t)i * C + c) = o;
        }
    } else {  // C == 64
        int grp = lane >> 4, cl = lane & 15, c = cl * 4;
        const Half4* gc = reinterpret_cast<const Half4*>(g) + cl;  // row stride 16 Half4
        float4 a0 = make_float4(0.f, 0.f, 0.f, 0.f), a1v = a0;

        if (grp == 0) a0 = h4_to_f4(gc[(size_t)i * 16]);

        for (; e + 8 <= e1; e += 8) {
            int s0 = srcs[e + grp], s1 = srcs[e + 4 + grp];
            float4 l0 = h4_to_f4(gc[(size_t)s0 * 16]);
            float4 l1 = h4_to_f4(gc[(size_t)s1 * 16]);
            a0.x += l0.x; a0.y += l0.y; a0.z += l0.z; a0.w += l0.w;
            a1v.x += l1.x; a1v.y += l1.y; a1v.z += l1.z; a1v.w += l1.w;
        }
        if (e + 4 <= e1) {
            int s0 = srcs[e + grp];
            float4 l0 = h4_to_f4(gc[(size_t)s0 * 16]);
            a0.x += l0.x; a0.y += l0.y; a0.z += l0.z; a0.w += l0.w;
            e += 4;
        }
        int rem = e1 - e;  // 0..3
        if (grp < rem) {
            int s0 = srcs[e + grp];
            float4 l0 = h4_to_f4(gc[(size_t)s0 * 16]);
            a1v.x += l0.x; a1v.y += l0.y; a1v.z += l0.z; a1v.w += l0.w;
        }

        float4 acc = make_float4(a0.x + a1v.x, a0.y + a1v.y, a0.z + a1v.z, a0.w + a1v.w);
        #pragma unroll
        for (int d = 16; d <= 32; d <<= 1) {
            acc.x += __shfl_xor(acc.x, d, 64);
            acc.y += __shfl_xor(acc.y, d, 64);
            acc.z += __shfl_xor(acc.z, d, 64);
            acc.w += __shfl_xor(acc.w, d, 64);
        }

        if (grp == 0) {
            float4 o = make_float4(di * acc.x, di * acc.y, di * acc.z, di * acc.w);
            if constexpr (BIAS) {
                float4 b = *reinterpret_cast<const float4*>(bias + c);
                o.x += b.x; o.y += b.y; o.z += b.z; o.w += b.w;
            }
            if constexpr (RELU) {
                o.x = fmaxf(o.x, 0.f); o.y = fmaxf(o.y, 0.f);
                o.z = fmaxf(o.z, 0.f); o.w = fmaxf(o.w, 0.f);
            }
            if constexpr (OUTH)
                *reinterpret_cast<Half4*>((__half*)outv + (size_t)i * C + c) = f4_to_h4(o);
            else
                *reinterpret_cast<float4*>((float*)outv + (size_t)i * C + c) = o;
        }
    }
}

// ---------------- pack W (f32 row-major [CIN][COUT]) into MFMA fragment order ----------------

template<int CIN, int COUT>
__global__ __launch_bounds__(256) void pack_w(const float* __restrict__ W, h8* __restrict__ Wp) {
    constexpr int NKS = CIN / 32, NCT = COUT / 16;
    int idx = blockIdx.x * 256 + threadIdx.x;
    if (idx >= NKS * NCT * 64) return;
    int l = idx & 63;
    int ct = (idx >> 6) % NCT;
    int ks = (idx >> 6) / NCT;
    int col = ct * 16 + (l & 15);
    int kb = ks * 32 + ((l >> 4) << 2);
    h8 t;
    #pragma unroll
    for (int j = 0; j < 8; ++j) {
        int k = kb + (j & 3) + ((j >> 2) << 4);
        t[j] = (_Float16)W[k * COUT + col];
    }
    Wp[idx] = t;
}

// ---------------- MFMA GEMM: out = epilogue(A[n][CIN] @ W[CIN][COUT]) ----------------
// EPI 0: out = half(acc * aux[row]);  EPI 1: out = half(relu(acc + aux[col]))
// Block: 4 waves x 32 rows = 128 rows. Wp pre-packed fragments.

template<int CIN, int COUT, int EPI>
__global__ __launch_bounds__(256) void mfma_gemm(const __half* __restrict__ A,
                                                 const h8* __restrict__ Wp,
                                                 const float* __restrict__ aux,
                                                 __half* __restrict__ out, int n) {
    constexpr int NKS = CIN / 32, NCT = COUT / 16;
    constexpr int FRAGS = NKS * NCT * 64;
    __shared__ h8 wlds[FRAGS];
    for (int idx = threadIdx.x; idx < FRAGS; idx += 256) wlds[idx] = Wp[idx];
    __syncthreads();

    int wid = threadIdx.x >> 6, lane = threadIdx.x & 63;
    int rowBase = blockIdx.x * 128 + wid * 32;
    int m = lane & 15;
    int kq = (lane >> 4) << 2;

    int row0 = min(rowBase + m, n - 1);
    int row1 = min(rowBase + 16 + m, n - 1);
    const __half* ar0 = A + (size_t)row0 * CIN;
    const __half* ar1 = A + (size_t)row1 * CIN;

    f32x4 acc[2][NCT];
    #pragma unroll
    for (int rt = 0; rt < 2; ++rt)
        #pragma unroll
        for (int ct = 0; ct < NCT; ++ct)
            acc[rt][ct] = f32x4{0.f, 0.f, 0.f, 0.f};

    #pragma unroll
    for (int ks = 0; ks < NKS; ++ks) {
        int kb = ks * 32 + kq;
        h8 a0, a1;
        *reinterpret_cast<short4*>(&a0) = *reinterpret_cast<const short4*>(ar0 + kb);
        *(reinterpret_cast<short4*>(&a0) + 1) = *reinterpret_cast<const short4*>(ar0 + kb + 16);
        *reinterpret_cast<short4*>(&a1) = *reinterpret_cast<const short4*>(ar1 + kb);
        *(reinterpret_cast<short4*>(&a1) + 1) = *reinterpret_cast<const short4*>(ar1 + kb + 16);
        #pragma unroll
        for (int ct = 0; ct < NCT; ++ct) {
            h8 b = wlds[(ks * NCT + ct) * 64 + lane];
            acc[0][ct] = __builtin_amdgcn_mfma_f32_16x16x32_f16(a0, b, acc[0][ct], 0, 0, 0);
            acc[1][ct] = __builtin_amdgcn_mfma_f32_16x16x32_f16(a1, b, acc[1][ct], 0, 0, 0);
        }
    }

    float bcol[NCT];
    if constexpr (EPI == 1) {
        #pragma unroll
        for (int ct = 0; ct < NCT; ++ct) bcol[ct] = aux[ct * 16 + m];
    }
    #pragma unroll
    for (int rt = 0; rt < 2; ++rt) {
        #pragma unroll
        for (int r = 0; r < 4; ++r) {
            int row = rowBase + rt * 16 + kq + r;
            if (row < n) {
                float d = 0.f;
                if constexpr (EPI == 0) d = aux[row];
                __half* orow = out + (size_t)row * COUT + m;
                #pragma unroll
                for (int ct = 0; ct < NCT; ++ct) {
                    float v = acc[rt][ct][r];
                    if constexpr (EPI == 0) v *= d;
                    else v = fmaxf(v + bcol[ct], 0.f);
                    orow[ct * 16] = __float2half(v);
                }
            }
        }
    }
}

// ---------------- launch ----------------

extern "C" void kernel_launch(void* const* d_in, const int* in_sizes, int n_in,
                              void* d_out, int out_size, void* d_ws, size_t ws_size,
                              hipStream_t stream) {
    const float* x  = (const float*)d_in[0];
    const int*   ei = (const int*)d_in[1];
    const float* W1 = (const float*)d_in[2];
    const float* b1 = (const float*)d_in[3];
    const float* W2 = (const float*)d_in[4];
    const float* b2 = (const float*)d_in[5];
    const float* W3 = (const float*)d_in[6];
    const float* b3 = (const float*)d_in[7];

    const int n = in_sizes[0] / 64;   // 50000
    const int e = in_sizes[1] / 2;    // 800000
    const int* src = ei;
    const int* dst = ei + e;
    const int nb = (n + 127) >> 7;    // 128-node buckets

    // workspace layout (4-byte units; 8B align for int2, 16B for h8)
    int*   ws_i = (int*)d_ws;
    float* ws_f = (float*)d_ws;
    size_t o = 0;
    int* bcnt    = ws_i + o; o += MAXNB;
    int* bbase   = ws_i + o; o += MAXNB + 2;
    int* bcursor = ws_i + o; o += MAXNB;
    int* offsets = ws_i + o; o += n + 8;
    int* srcs    = ws_i + o; o += e;
    float* dis   = ws_f + o; o += n;
    o = (o + 1) & ~(size_t)1;
    int2* binned = (int2*)(ws_i + o); o += (size_t)e * 2;
    o = (o + 3) & ~(size_t)3;
    h8* Wp1 = (h8*)(ws_i + o); o += 4096;   // 1024 frags * 16B
    h8* Wp2 = (h8*)(ws_i + o); o += 8192;   // 2048 frags
    h8* Wp3 = (h8*)(ws_i + o); o += 4096;   // 1024 frags
    float* R1 = ws_f + o; o += (size_t)n * 64;   // a1h (n*64 h), then h2h (n*128 h)
    float* R2 = ws_f + o; o += (size_t)n * 64;   // h1h (n*128 h), then g3 (n*64 h)

    // d_out doubles as scratch: x16 (half 64w), then g2 (half 128w), then final out
    Half4*  x16 = (Half4*)d_out;
    __half* g2  = (__half*)d_out;
    __half* a1h = (__half*)R1;
    __half* h1h = (__half*)R2;
    __half* h2h = (__half*)R1;
    __half* g3  = (__half*)R2;
    float*  out = (float*)d_out;

    const int B = 256;
    // CSR build (two-level counting sort)
    hipMemsetAsync(bcnt, 0, MAXNB * sizeof(int), stream);
    bucket_count<<<256, B, 0, stream>>>(dst, bcnt, e, nb);
    scan_buckets<<<1, 64, 0, stream>>>(bcnt, bbase, bcursor, nb);
    bin_edges<<<(e + R3_CHUNK - 1) / R3_CHUNK, B, 0, stream>>>(src, dst, bcursor, binned, e, nb);
    finalize_csr<<<nb, 128, 0, stream>>>(binned, bbase, offsets, srcs, dis, n, nb);
    prep_x_kernel<<<(n * 16 + B - 1) / B, B, 0, stream>>>(x, dis, x16, n);
    // pack weights into MFMA fragment order (once per call)
    pack_w<64, 128><<<4, B, 0, stream>>>(W1, Wp1);
    pack_w<128, 128><<<8, B, 0, stream>>>(W2, Wp2);
    pack_w<128, 64><<<4, B, 0, stream>>>(W3, Wp3);

    dim3 agrid((n + 3) / 4);
    dim3 ggrid((n + 127) / 128);

    // L1: a1h = half(dis*agg(x16)); h1h = half(relu(a1@W1+b1))
    aggregate_h<64, false, false, true><<<agrid, 256, 0, stream>>>((const __half*)x16, srcs, offsets, dis, nullptr, a1h, n);
    mfma_gemm<64, 128, 1><<<ggrid, 256, 0, stream>>>(a1h, Wp1, b1, h1h, n);
    // L2: g2 = half((h1@W2)*dis); h2h = half(relu(dis*agg(g2)+b2))
    mfma_gemm<128, 128, 0><<<ggrid, 256, 0, stream>>>(h1h, Wp2, dis, g2, n);
    aggregate_h<128, true, true, true><<<agrid, 256, 0, stream>>>(g2, srcs, offsets, dis, b2, h2h, n);
    // L3: g3 = half((h2@W3)*dis); out = dis*agg(g3)+b3
    mfma_gemm<128, 64, 0><<<ggrid, 256, 0, stream>>>(h2h, Wp3, dis, g3, n);
    aggregate_h<64, false, true, false><<<agrid, 256, 0, stream>>>(g3, srcs, offsets, dis, b3, out, n);
}

// Round 9
// 177.308 us; speedup vs baseline: 2.2784x; 1.0077x over previous
//
#include <hip/hip_runtime.h>
#include <hip/hip_fp16.h>

// GCN 3-layer, fp16 payloads + MFMA GEMMs (f32 accumulate):
// L1: a1h = half(dis.*agg(x16)) ; h1h = half(relu(a1@W1+b1))   [agg64h + mfma_gemm EPI1]
// L2: g2 = half((h1@W2).*dis)   ; h2h = half(relu(dis.*agg(g2)+b2)) [mfma EPI0 + agg128h]
// L3: g3 = half((h2@W3).*dis)   ; out = dis.*agg(g3)+b3        [mfma EPI0 + agg64h f32]
// dis[i] = rsqrt(1 + indegree[i]); x16 = half(x .* dis) produced inside finalize_csr.
// CSR build: two-level counting sort (128-node buckets), packed 4B edge records (n<=65536).

typedef _Float16 h8 __attribute__((ext_vector_type(8)));
typedef float f32x4 __attribute__((ext_vector_type(4)));

struct alignas(8) Half4 { __half2 lo, hi; };

__device__ inline float4 h4_to_f4(Half4 h) {
    float2 a = __half22float2(h.lo), b = __half22float2(h.hi);
    return make_float4(a.x, a.y, b.x, b.y);
}
__device__ inline Half4 f4_to_h4(float4 v) {
    Half4 h; h.lo = __floats2half2_rn(v.x, v.y); h.hi = __floats2half2_rn(v.z, v.w); return h;
}

#define MAXNB 512   // buckets of 128 nodes; covers n <= 65536

// ---------------- R1: bucket histogram ----------------

__global__ __launch_bounds__(256) void bucket_count(const int* __restrict__ dst,
                                                    int* __restrict__ bcnt, int e, int nb) {
    __shared__ int h[MAXNB];
    int tid = threadIdx.x;
    for (int i = tid; i < nb; i += 256) h[i] = 0;
    __syncthreads();
    for (int i = blockIdx.x * 256 + tid; i < e; i += gridDim.x * 256)
        atomicAdd(&h[dst[i] >> 7], 1);
    __syncthreads();
    for (int i = tid; i < nb; i += 256) {
        int c = h[i];
        if (c) atomicAdd(&bcnt[i], c);
    }
}

// ---------------- R2: single-wave exclusive scan of bucket counts ----------------

__global__ void scan_buckets(const int* __restrict__ bcnt, int* __restrict__ bbase,
                             int* __restrict__ bcursor, int nb) {
    int lane = threadIdx.x;  // 64 threads
    int running = 0;
    for (int base = 0; base < nb; base += 64) {
        int idx = base + lane;
        int v = (idx < nb) ? bcnt[idx] : 0;
        int x = v;
        #pragma unroll
        for (int d = 1; d < 64; d <<= 1) {
            int t = __shfl_up(x, d, 64);
            if (lane >= d) x += t;
        }
        if (idx < nb) { bbase[idx] = running + x - v; bcursor[idx] = running + x - v; }
        running += __shfl(x, 63, 64);
    }
    if (lane == 0) bbase[nb] = running;
}

// ---------------- R3: bin edges into bucket segments ----------------
// PACKED (n<=65536): record = src | (dst&127)<<16  (4 B). Else int2 (src,dst).

#define R3_CHUNK 4096

template<bool PACKED>
__global__ __launch_bounds__(256) void bin_edges(const int* __restrict__ src,
                                                 const int* __restrict__ dst,
                                                 int* __restrict__ bcursor,
                                                 void* __restrict__ binned_, int e, int nb) {
    __shared__ int h[MAXNB];
    __shared__ int gp[MAXNB];
    int tid = threadIdx.x;
    for (int i = tid; i < nb; i += 256) h[i] = 0;
    __syncthreads();
    int lo = blockIdx.x * R3_CHUNK, hi = min(lo + R3_CHUNK, e);
    for (int i = lo + tid; i < hi; i += 256) atomicAdd(&h[dst[i] >> 7], 1);
    __syncthreads();
    for (int b = tid; b < nb; b += 256) {
        int c = h[b];
        if (c) gp[b] = atomicAdd(&bcursor[b], c);
        h[b] = 0;  // reuse as local cursor
    }
    __syncthreads();
    for (int i = lo + tid; i < hi; i += 256) {
        int d = dst[i];
        int b = d >> 7;
        int p = atomicAdd(&h[b], 1);
        if constexpr (PACKED)
            ((unsigned*)binned_)[gp[b] + p] = (unsigned)src[i] | ((unsigned)(d & 127) << 16);
        else
            ((int2*)binned_)[gp[b] + p] = make_int2(src[i], d);
    }
}

// ---------------- R4: per-bucket finalize + x16 conversion ----------------

template<bool PACKED>
__global__ __launch_bounds__(128) void finalize_csr(const void* __restrict__ binned_,
                                                    const int* __restrict__ bbase,
                                                    int* __restrict__ offsets,
                                                    int* __restrict__ srcs,
                                                    float* __restrict__ dis,
                                                    const float* __restrict__ x,
                                                    Half4* __restrict__ x16,
                                                    int n, int nb) {
    int b = blockIdx.x;
    int tid = threadIdx.x;  // 128 threads, one node each
    int nb0 = b << 7;
    int segLo = bbase[b], segHi = bbase[b + 1];

    __shared__ int cnt[128];
    __shared__ int cur[128];
    __shared__ float sdis[128];
    __shared__ int wtot;
    cnt[tid] = 0;
    __syncthreads();
    if constexpr (PACKED) {
        const unsigned* binned = (const unsigned*)binned_;
        for (int i = segLo + tid; i < segHi; i += 128)
            atomicAdd(&cnt[(binned[i] >> 16) & 127], 1);
    } else {
        const int2* binned = (const int2*)binned_;
        for (int i = segLo + tid; i < segHi; i += 128)
            atomicAdd(&cnt[binned[i].y & 127], 1);
    }
    __syncthreads();

    int c = cnt[tid];
    int lane = tid & 63, w = tid >> 6;
    int x_ = c;
    #pragma unroll
    for (int d = 1; d < 64; d <<= 1) {
        int t = __shfl_up(x_, d, 64);
        if (lane >= d) x_ += t;
    }
    if (w == 0 && lane == 63) wtot = x_;
    __syncthreads();
    int excl = x_ - c + (w ? wtot : 0);

    int node = nb0 + tid;
    float dv = rsqrtf((float)(c + 1));
    if (node < n) {
        offsets[node] = segLo + excl;
        dis[node] = dv;
    }
    if (b == nb - 1 && tid == 0) offsets[n] = segHi;
    cur[tid] = excl;
    sdis[tid] = dv;
    __syncthreads();

    if constexpr (PACKED) {
        const unsigned* binned = (const unsigned*)binned_;
        for (int i = segLo + tid; i < segHi; i += 128) {
            unsigned v = binned[i];
            int ln = (v >> 16) & 127;
            int p = atomicAdd(&cur[ln], 1);
            srcs[segLo + p] = (int)(v & 0xFFFFu);
        }
    } else {
        const int2* binned = (const int2*)binned_;
        for (int i = segLo + tid; i < segHi; i += 128) {
            int2 v = binned[i];
            int ln = v.y & 127;
            int p = atomicAdd(&cur[ln], 1);
            srcs[segLo + p] = v.x;
        }
    }

    // x16 rows for this bucket's nodes: x16[node] = half(x[node] * dis[node])
    int rows = min(128, n - nb0);
    if (rows > 0) {
        int limit = rows * 16;  // Half4 units (64 ch = 16 Half4)
        const float4* xr = reinterpret_cast<const float4*>(x) + (size_t)nb0 * 16;
        Half4* xo = x16 + (size_t)nb0 * 16;
        for (int idx = tid; idx < limit; idx += 128) {
            float d = sdis[idx >> 4];
            float4 v = xr[idx];
            xo[idx] = f4_to_h4(make_float4(v.x * d, v.y * d, v.z * d, v.w * d));
        }
    }
}

// ---------------- aggregate (fp16 payload, f32 accumulate) ----------------
// out[i] = [relu]( dis[i]*( g[i] + sum_edges g[s] ) [+ bias] ), payloads prescaled.
// OUTH: write half output (Half4) instead of float4.

template<int C, bool RELU, bool BIAS, bool OUTH>
__global__ __launch_bounds__(256) void aggregate_h(const __half* __restrict__ g,
                                                   const int* __restrict__ srcs,
                                                   const int* __restrict__ offsets,
                                                   const float* __restrict__ dis,
                                                   const float* __restrict__ bias,
                                                   void* __restrict__ outv, int n) {
    int wid = threadIdx.x >> 6, lane = threadIdx.x & 63;
    int i = blockIdx.x * 4 + wid;
    if (i >= n) return;
    float di = dis[i];
    int e0 = offsets[i], e1 = offsets[i + 1];
    int e = e0;

    if constexpr (C == 128) {
        int half_ = lane >> 5, cl = lane & 31, c = cl * 4;
        const Half4* gc = reinterpret_cast<const Half4*>(g) + cl;  // row stride 32 Half4
        float4 a0 = make_float4(0.f, 0.f, 0.f, 0.f), a1v = a0, a2 = a0, a3 = a0;

        if (half_ == 0) a0 = h4_to_f4(gc[(size_t)i * 32]);

        for (; e + 8 <= e1; e += 8) {
            int s0 = srcs[e + half_], s1 = srcs[e + 2 + half_];
            int s2 = srcs[e + 4 + half_], s3 = srcs[e + 6 + half_];
            float4 l0 = h4_to_f4(gc[(size_t)s0 * 32]);
            float4 l1 = h4_to_f4(gc[(size_t)s1 * 32]);
            float4 l2 = h4_to_f4(gc[(size_t)s2 * 32]);
            float4 l3 = h4_to_f4(gc[(size_t)s3 * 32]);
            a0.x += l0.x; a0.y += l0.y; a0.z += l0.z; a0.w += l0.w;
            a1v.x += l1.x; a1v.y += l1.y; a1v.z += l1.z; a1v.w += l1.w;
            a2.x += l2.x; a2.y += l2.y; a2.z += l2.z; a2.w += l2.w;
            a3.x += l3.x; a3.y += l3.y; a3.z += l3.z; a3.w += l3.w;
        }
        if (e + 4 <= e1) {
            int s0 = srcs[e + half_], s1 = srcs[e + 2 + half_];
            float4 l0 = h4_to_f4(gc[(size_t)s0 * 32]);
            float4 l1 = h4_to_f4(gc[(size_t)s1 * 32]);
            a0.x += l0.x; a0.y += l0.y; a0.z += l0.z; a0.w += l0.w;
            a1v.x += l1.x; a1v.y += l1.y; a1v.z += l1.z; a1v.w += l1.w;
            e += 4;
        }
        if (e + 2 <= e1) {
            int s0 = srcs[e + half_];
            float4 l0 = h4_to_f4(gc[(size_t)s0 * 32]);
            a2.x += l0.x; a2.y += l0.y; a2.z += l0.z; a2.w += l0.w;
            e += 2;
        }
        if (e < e1 && half_ == 0) {
            int s0 = srcs[e];
            float4 l0 = h4_to_f4(gc[(size_t)s0 * 32]);
            a3.x += l0.x; a3.y += l0.y; a3.z += l0.z; a3.w += l0.w;
        }

        float4 acc = make_float4((a0.x + a1v.x) + (a2.x + a3.x), (a0.y + a1v.y) + (a2.y + a3.y),
                                 (a0.z + a1v.z) + (a2.z + a3.z), (a0.w + a1v.w) + (a2.w + a3.w));
        acc.x += __shfl_xor(acc.x, 32, 64);
        acc.y += __shfl_xor(acc.y, 32, 64);
        acc.z += __shfl_xor(acc.z, 32, 64);
        acc.w += __shfl_xor(acc.w, 32, 64);

        if (half_ == 0) {
            float4 o = make_float4(di * acc.x, di * acc.y, di * acc.z, di * acc.w);
            if constexpr (BIAS) {
                float4 b = *reinterpret_cast<const float4*>(bias + c);
                o.x += b.x; o.y += b.y; o.z += b.z; o.w += b.w;
            }
            if constexpr (RELU) {
                o.x = fmaxf(o.x, 0.f); o.y = fmaxf(o.y, 0.f);
                o.z = fmaxf(o.z, 0.f); o.w = fmaxf(o.w, 0.f);
            }
            if constexpr (OUTH)
                *reinterpret_cast<Half4*>((__half*)outv + (size_t)i * C + c) = f4_to_h4(o);
            else
                *reinterpret_cast<float4*>((float*)outv + (size_t)i * C + c) = o;
        }
    } else {  // C == 64
        int grp = lane >> 4, cl = lane & 15, c = cl * 4;
        const Half4* gc = reinterpret_cast<const Half4*>(g) + cl;  // row stride 16 Half4
        float4 a0 = make_float4(0.f, 0.f, 0.f, 0.f), a1v = a0;

        if (grp == 0) a0 = h4_to_f4(gc[(size_t)i * 16]);

        for (; e + 8 <= e1; e += 8) {
            int s0 = srcs[e + grp], s1 = srcs[e + 4 + grp];
            float4 l0 = h4_to_f4(gc[(size_t)s0 * 16]);
            float4 l1 = h4_to_f4(gc[(size_t)s1 * 16]);
            a0.x += l0.x; a0.y += l0.y; a0.z += l0.z; a0.w += l0.w;
            a1v.x += l1.x; a1v.y += l1.y; a1v.z += l1.z; a1v.w += l1.w;
        }
        if (e + 4 <= e1) {
            int s0 = srcs[e + grp];
            float4 l0 = h4_to_f4(gc[(size_t)s0 * 16]);
            a0.x += l0.x; a0.y += l0.y; a0.z += l0.z; a0.w += l0.w;
            e += 4;
        }
        int rem = e1 - e;  // 0..3
        if (grp < rem) {
            int s0 = srcs[e + grp];
            float4 l0 = h4_to_f4(gc[(size_t)s0 * 16]);
            a1v.x += l0.x; a1v.y += l0.y; a1v.z += l0.z; a1v.w += l0.w;
        }

        float4 acc = make_float4(a0.x + a1v.x, a0.y + a1v.y, a0.z + a1v.z, a0.w + a1v.w);
        #pragma unroll
        for (int d = 16; d <= 32; d <<= 1) {
            acc.x += __shfl_xor(acc.x, d, 64);
            acc.y += __shfl_xor(acc.y, d, 64);
            acc.z += __shfl_xor(acc.z, d, 64);
            acc.w += __shfl_xor(acc.w, d, 64);
        }

        if (grp == 0) {
            float4 o = make_float4(di * acc.x, di * acc.y, di * acc.z, di * acc.w);
            if constexpr (BIAS) {
                float4 b = *reinterpret_cast<const float4*>(bias + c);
                o.x += b.x; o.y += b.y; o.z += b.z; o.w += b.w;
            }
            if constexpr (RELU) {
                o.x = fmaxf(o.x, 0.f); o.y = fmaxf(o.y, 0.f);
                o.z = fmaxf(o.z, 0.f); o.w = fmaxf(o.w, 0.f);
            }
            if constexpr (OUTH)
                *reinterpret_cast<Half4*>((__half*)outv + (size_t)i * C + c) = f4_to_h4(o);
            else
                *reinterpret_cast<float4*>((float*)outv + (size_t)i * C + c) = o;
        }
    }
}

// ---------------- pack all W into MFMA fragment order (one kernel) ----------------
// frag layout (16x16x32 f16): lane l elem j -> k=(l>>4)*4+(j&3)+16*(j>>2), col=l&15.

template<int CIN, int COUT>
__device__ inline void pack_frag(const float* __restrict__ W, h8* __restrict__ Wp, int idx) {
    constexpr int NCT = COUT / 16;
    int l = idx & 63;
    int ct = (idx >> 6) % NCT;
    int ks = (idx >> 6) / NCT;
    int col = ct * 16 + (l & 15);
    int kb = ks * 32 + ((l >> 4) << 2);
    h8 t;
    #pragma unroll
    for (int j = 0; j < 8; ++j) {
        int k = kb + (j & 3) + ((j >> 2) << 4);
        t[j] = (_Float16)W[k * COUT + col];
    }
    Wp[idx] = t;
}

__global__ __launch_bounds__(256) void pack_all(const float* __restrict__ W1,
                                                const float* __restrict__ W2,
                                                const float* __restrict__ W3,
                                                h8* __restrict__ Wp1, h8* __restrict__ Wp2,
                                                h8* __restrict__ Wp3) {
    int idx = blockIdx.x * 256 + threadIdx.x;
    if (idx < 1024)      pack_frag<64, 128>(W1, Wp1, idx);          // 2*8*64
    else if (idx < 3072) pack_frag<128, 128>(W2, Wp2, idx - 1024);  // 4*8*64
    else if (idx < 4096) pack_frag<128, 64>(W3, Wp3, idx - 3072);   // 4*4*64
}

// ---------------- MFMA GEMM: out = epilogue(A[n][CIN] @ W[CIN][COUT]) ----------------
// EPI 0: out = half(acc * aux[row]);  EPI 1: out = half(relu(acc + aux[col]))

template<int CIN, int COUT, int EPI>
__global__ __launch_bounds__(256) void mfma_gemm(const __half* __restrict__ A,
                                                 const h8* __restrict__ Wp,
                                                 const float* __restrict__ aux,
                                                 __half* __restrict__ out, int n) {
    constexpr int NKS = CIN / 32, NCT = COUT / 16;
    constexpr int FRAGS = NKS * NCT * 64;
    __shared__ h8 wlds[FRAGS];
    for (int idx = threadIdx.x; idx < FRAGS; idx += 256) wlds[idx] = Wp[idx];
    __syncthreads();

    int wid = threadIdx.x >> 6, lane = threadIdx.x & 63;
    int rowBase = blockIdx.x * 128 + wid * 32;
    int m = lane & 15;
    int kq = (lane >> 4) << 2;

    int row0 = min(rowBase + m, n - 1);
    int row1 = min(rowBase + 16 + m, n - 1);
    const __half* ar0 = A + (size_t)row0 * CIN;
    const __half* ar1 = A + (size_t)row1 * CIN;

    f32x4 acc[2][NCT];
    #pragma unroll
    for (int rt = 0; rt < 2; ++rt)
        #pragma unroll
        for (int ct = 0; ct < NCT; ++ct)
            acc[rt][ct] = f32x4{0.f, 0.f, 0.f, 0.f};

    #pragma unroll
    for (int ks = 0; ks < NKS; ++ks) {
        int kb = ks * 32 + kq;
        h8 a0, a1;
        *reinterpret_cast<short4*>(&a0) = *reinterpret_cast<const short4*>(ar0 + kb);
        *(reinterpret_cast<short4*>(&a0) + 1) = *reinterpret_cast<const short4*>(ar0 + kb + 16);
        *reinterpret_cast<short4*>(&a1) = *reinterpret_cast<const short4*>(ar1 + kb);
        *(reinterpret_cast<short4*>(&a1) + 1) = *reinterpret_cast<const short4*>(ar1 + kb + 16);
        #pragma unroll
        for (int ct = 0; ct < NCT; ++ct) {
            h8 b = wlds[(ks * NCT + ct) * 64 + lane];
            acc[0][ct] = __builtin_amdgcn_mfma_f32_16x16x32_f16(a0, b, acc[0][ct], 0, 0, 0);
            acc[1][ct] = __builtin_amdgcn_mfma_f32_16x16x32_f16(a1, b, acc[1][ct], 0, 0, 0);
        }
    }

    float bcol[NCT];
    if constexpr (EPI == 1) {
        #pragma unroll
        for (int ct = 0; ct < NCT; ++ct) bcol[ct] = aux[ct * 16 + m];
    }
    #pragma unroll
    for (int rt = 0; rt < 2; ++rt) {
        #pragma unroll
        for (int r = 0; r < 4; ++r) {
            int row = rowBase + rt * 16 + kq + r;
            if (row < n) {
                float d = 0.f;
                if constexpr (EPI == 0) d = aux[row];
                __half* orow = out + (size_t)row * COUT + m;
                #pragma unroll
                for (int ct = 0; ct < NCT; ++ct) {
                    float v = acc[rt][ct][r];
                    if constexpr (EPI == 0) v *= d;
                    else v = fmaxf(v + bcol[ct], 0.f);
                    orow[ct * 16] = __float2half(v);
                }
            }
        }
    }
}

// ---------------- launch ----------------

extern "C" void kernel_launch(void* const* d_in, const int* in_sizes, int n_in,
                              void* d_out, int out_size, void* d_ws, size_t ws_size,
                              hipStream_t stream) {
    const float* x  = (const float*)d_in[0];
    const int*   ei = (const int*)d_in[1];
    const float* W1 = (const float*)d_in[2];
    const float* b1 = (const float*)d_in[3];
    const float* W2 = (const float*)d_in[4];
    const float* b2 = (const float*)d_in[5];
    const float* W3 = (const float*)d_in[6];
    const float* b3 = (const float*)d_in[7];

    const int n = in_sizes[0] / 64;   // 50000
    const int e = in_sizes[1] / 2;    // 800000
    const int* src = ei;
    const int* dst = ei + e;
    const int nb = (n + 127) >> 7;    // 128-node buckets
    const bool packed = (n <= 65536);

    // workspace layout (4-byte units; 8B align for int2, 16B for h8)
    int*   ws_i = (int*)d_ws;
    float* ws_f = (float*)d_ws;
    size_t o = 0;
    int* bcnt    = ws_i + o; o += MAXNB;
    int* bbase   = ws_i + o; o += MAXNB + 2;
    int* bcursor = ws_i + o; o += MAXNB;
    int* offsets = ws_i + o; o += n + 8;
    int* srcs    = ws_i + o; o += e;
    float* dis   = ws_f + o; o += n;
    o = (o + 1) & ~(size_t)1;
    void* binned = (void*)(ws_i + o); o += (size_t)e * 2;  // reserve int2 worst case
    o = (o + 3) & ~(size_t)3;
    h8* Wp1 = (h8*)(ws_i + o); o += 4096;   // 1024 frags * 16B
    h8* Wp2 = (h8*)(ws_i + o); o += 8192;   // 2048 frags
    h8* Wp3 = (h8*)(ws_i + o); o += 4096;   // 1024 frags
    float* R1 = ws_f + o; o += (size_t)n * 64;   // a1h (n*64 h), then h2h (n*128 h)
    float* R2 = ws_f + o; o += (size_t)n * 64;   // h1h (n*128 h), then g3 (n*64 h)

    // d_out doubles as scratch: x16 (half 64w), then g2 (half 128w), then final out
    Half4*  x16 = (Half4*)d_out;
    __half* g2  = (__half*)d_out;
    __half* a1h = (__half*)R1;
    __half* h1h = (__half*)R2;
    __half* h2h = (__half*)R1;
    __half* g3  = (__half*)R2;
    float*  out = (float*)d_out;

    const int B = 256;
    // CSR build (two-level counting sort) + x16 prep + weight pack
    hipMemsetAsync(bcnt, 0, MAXNB * sizeof(int), stream);
    bucket_count<<<256, B, 0, stream>>>(dst, bcnt, e, nb);
    scan_buckets<<<1, 64, 0, stream>>>(bcnt, bbase, bcursor, nb);
    if (packed) {
        bin_edges<true><<<(e + R3_CHUNK - 1) / R3_CHUNK, B, 0, stream>>>(src, dst, bcursor, binned, e, nb);
        finalize_csr<true><<<nb, 128, 0, stream>>>(binned, bbase, offsets, srcs, dis, x, x16, n, nb);
    } else {
        bin_edges<false><<<(e + R3_CHUNK - 1) / R3_CHUNK, B, 0, stream>>>(src, dst, bcursor, binned, e, nb);
        finalize_csr<false><<<nb, 128, 0, stream>>>(binned, bbase, offsets, srcs, dis, x, x16, n, nb);
    }
    pack_all<<<16, B, 0, stream>>>(W1, W2, W3, Wp1, Wp2, Wp3);

    dim3 agrid((n + 3) / 4);
    dim3 ggrid((n + 127) / 128);

    // L1: a1h = half(dis*agg(x16)); h1h = half(relu(a1@W1+b1))
    aggregate_h<64, false, false, true><<<agrid, 256, 0, stream>>>((const __half*)x16, srcs, offsets, dis, nullptr, a1h, n);
    mfma_gemm<64, 128, 1><<<ggrid, 256, 0, stream>>>(a1h, Wp1, b1, h1h, n);
    // L2: g2 = half((h1@W2)*dis); h2h = half(relu(dis*agg(g2)+b2))
    mfma_gemm<128, 128, 0><<<ggrid, 256, 0, stream>>>(h1h, Wp2, dis, g2, n);
    aggregate_h<128, true, true, true><<<agrid, 256, 0, stream>>>(g2, srcs, offsets, dis, b2, h2h, n);
    // L3: g3 = half((h2@W3)*dis); out = dis*agg(g3)+b3
    mfma_gemm<128, 64, 0><<<ggrid, 256, 0, stream>>>(h2h, Wp3, dis, g3, n);
    aggregate_h<64, false, true, false><<<agrid, 256, 0, stream>>>(g3, srcs, offsets, dis, b3, out, n);
}

// Round 10
// 174.704 us; speedup vs baseline: 2.3123x; 1.0149x over previous
//
#include <hip/hip_runtime.h>
#include <hip/hip_fp16.h>

// GCN 3-layer, fp16 payloads + MFMA GEMMs (f32 accumulate):
// L1: a1h = half(dis.*agg(x16)) ; h1h = half(relu(a1@W1+b1))   [agg64h + mfma_gemm EPI1]
// L2: g2 = half((h1@W2).*dis)   ; h2h = half(relu(dis.*agg(g2)+b2)) [mfma EPI0 + agg128h]
// L3: g3 = half((h2@W3).*dis)   ; out = dis.*agg(g3)+b3        [mfma EPI0 + agg64h f32]
// dis[i] = rsqrt(1 + indegree[i]); x16 = half(x .* dis) produced inside finalize_csr.
// CSR build: two-level counting sort (128-node buckets), packed 4B edge records (n<=65536).
// bcnt zeroing fused into pack_all (extra block) -- no hipMemsetAsync graph node.

typedef _Float16 h8 __attribute__((ext_vector_type(8)));
typedef float f32x4 __attribute__((ext_vector_type(4)));

struct alignas(8) Half4 { __half2 lo, hi; };

__device__ inline float4 h4_to_f4(Half4 h) {
    float2 a = __half22float2(h.lo), b = __half22float2(h.hi);
    return make_float4(a.x, a.y, b.x, b.y);
}
__device__ inline Half4 f4_to_h4(float4 v) {
    Half4 h; h.lo = __floats2half2_rn(v.x, v.y); h.hi = __floats2half2_rn(v.z, v.w); return h;
}

#define MAXNB 512   // buckets of 128 nodes; covers n <= 65536

// ---------------- R1: bucket histogram ----------------

__global__ __launch_bounds__(256) void bucket_count(const int* __restrict__ dst,
                                                    int* __restrict__ bcnt, int e, int nb) {
    __shared__ int h[MAXNB];
    int tid = threadIdx.x;
    for (int i = tid; i < nb; i += 256) h[i] = 0;
    __syncthreads();
    for (int i = blockIdx.x * 256 + tid; i < e; i += gridDim.x * 256)
        atomicAdd(&h[dst[i] >> 7], 1);
    __syncthreads();
    for (int i = tid; i < nb; i += 256) {
        int c = h[i];
        if (c) atomicAdd(&bcnt[i], c);
    }
}

// ---------------- R2: single-wave exclusive scan of bucket counts ----------------

__global__ void scan_buckets(const int* __restrict__ bcnt, int* __restrict__ bbase,
                             int* __restrict__ bcursor, int nb) {
    int lane = threadIdx.x;  // 64 threads
    int running = 0;
    for (int base = 0; base < nb; base += 64) {
        int idx = base + lane;
        int v = (idx < nb) ? bcnt[idx] : 0;
        int x = v;
        #pragma unroll
        for (int d = 1; d < 64; d <<= 1) {
            int t = __shfl_up(x, d, 64);
            if (lane >= d) x += t;
        }
        if (idx < nb) { bbase[idx] = running + x - v; bcursor[idx] = running + x - v; }
        running += __shfl(x, 63, 64);
    }
    if (lane == 0) bbase[nb] = running;
}

// ---------------- R3: bin edges into bucket segments ----------------
// PACKED (n<=65536): record = src | (dst&127)<<16  (4 B). Else int2 (src,dst).

#define R3_CHUNK 4096

template<bool PACKED>
__global__ __launch_bounds__(256) void bin_edges(const int* __restrict__ src,
                                                 const int* __restrict__ dst,
                                                 int* __restrict__ bcursor,
                                                 void* __restrict__ binned_, int e, int nb) {
    __shared__ int h[MAXNB];
    __shared__ int gp[MAXNB];
    int tid = threadIdx.x;
    for (int i = tid; i < nb; i += 256) h[i] = 0;
    __syncthreads();
    int lo = blockIdx.x * R3_CHUNK, hi = min(lo + R3_CHUNK, e);
    for (int i = lo + tid; i < hi; i += 256) atomicAdd(&h[dst[i] >> 7], 1);
    __syncthreads();
    for (int b = tid; b < nb; b += 256) {
        int c = h[b];
        if (c) gp[b] = atomicAdd(&bcursor[b], c);
        h[b] = 0;  // reuse as local cursor
    }
    __syncthreads();
    for (int i = lo + tid; i < hi; i += 256) {
        int d = dst[i];
        int b = d >> 7;
        int p = atomicAdd(&h[b], 1);
        if constexpr (PACKED)
            ((unsigned*)binned_)[gp[b] + p] = (unsigned)src[i] | ((unsigned)(d & 127) << 16);
        else
            ((int2*)binned_)[gp[b] + p] = make_int2(src[i], d);
    }
}

// ---------------- R4: per-bucket finalize + x16 conversion ----------------

template<bool PACKED>
__global__ __launch_bounds__(128) void finalize_csr(const void* __restrict__ binned_,
                                                    const int* __restrict__ bbase,
                                                    int* __restrict__ offsets,
                                                    int* __restrict__ srcs,
                                                    float* __restrict__ dis,
                                                    const float* __restrict__ x,
                                                    Half4* __restrict__ x16,
                                                    int n, int nb) {
    int b = blockIdx.x;
    int tid = threadIdx.x;  // 128 threads, one node each
    int nb0 = b << 7;
    int segLo = bbase[b], segHi = bbase[b + 1];

    __shared__ int cnt[128];
    __shared__ int cur[128];
    __shared__ float sdis[128];
    __shared__ int wtot;
    cnt[tid] = 0;
    __syncthreads();
    if constexpr (PACKED) {
        const unsigned* binned = (const unsigned*)binned_;
        for (int i = segLo + tid; i < segHi; i += 128)
            atomicAdd(&cnt[(binned[i] >> 16) & 127], 1);
    } else {
        const int2* binned = (const int2*)binned_;
        for (int i = segLo + tid; i < segHi; i += 128)
            atomicAdd(&cnt[binned[i].y & 127], 1);
    }
    __syncthreads();

    int c = cnt[tid];
    int lane = tid & 63, w = tid >> 6;
    int x_ = c;
    #pragma unroll
    for (int d = 1; d < 64; d <<= 1) {
        int t = __shfl_up(x_, d, 64);
        if (lane >= d) x_ += t;
    }
    if (w == 0 && lane == 63) wtot = x_;
    __syncthreads();
    int excl = x_ - c + (w ? wtot : 0);

    int node = nb0 + tid;
    float dv = rsqrtf((float)(c + 1));
    if (node < n) {
        offsets[node] = segLo + excl;
        dis[node] = dv;
    }
    if (b == nb - 1 && tid == 0) offsets[n] = segHi;
    cur[tid] = excl;
    sdis[tid] = dv;
    __syncthreads();

    if constexpr (PACKED) {
        const unsigned* binned = (const unsigned*)binned_;
        for (int i = segLo + tid; i < segHi; i += 128) {
            unsigned v = binned[i];
            int ln = (v >> 16) & 127;
            int p = atomicAdd(&cur[ln], 1);
            srcs[segLo + p] = (int)(v & 0xFFFFu);
        }
    } else {
        const int2* binned = (const int2*)binned_;
        for (int i = segLo + tid; i < segHi; i += 128) {
            int2 v = binned[i];
            int ln = v.y & 127;
            int p = atomicAdd(&cur[ln], 1);
            srcs[segLo + p] = v.x;
        }
    }

    // x16 rows for this bucket's nodes: x16[node] = half(x[node] * dis[node])
    int rows = min(128, n - nb0);
    if (rows > 0) {
        int limit = rows * 16;  // Half4 units (64 ch = 16 Half4)
        const float4* xr = reinterpret_cast<const float4*>(x) + (size_t)nb0 * 16;
        Half4* xo = x16 + (size_t)nb0 * 16;
        for (int idx = tid; idx < limit; idx += 128) {
            float d = sdis[idx >> 4];
            float4 v = xr[idx];
            xo[idx] = f4_to_h4(make_float4(v.x * d, v.y * d, v.z * d, v.w * d));
        }
    }
}

// ---------------- aggregate (fp16 payload, f32 accumulate) ----------------
// out[i] = [relu]( dis[i]*( g[i] + sum_edges g[s] ) [+ bias] ), payloads prescaled.
// OUTH: write half output (Half4) instead of float4.

template<int C, bool RELU, bool BIAS, bool OUTH>
__global__ __launch_bounds__(256) void aggregate_h(const __half* __restrict__ g,
                                                   const int* __restrict__ srcs,
                                                   const int* __restrict__ offsets,
                                                   const float* __restrict__ dis,
                                                   const float* __restrict__ bias,
                                                   void* __restrict__ outv, int n) {
    int wid = threadIdx.x >> 6, lane = threadIdx.x & 63;
    int i = blockIdx.x * 4 + wid;
    if (i >= n) return;
    float di = dis[i];
    int e0 = offsets[i], e1 = offsets[i + 1];
    int e = e0;

    if constexpr (C == 128) {
        int half_ = lane >> 5, cl = lane & 31, c = cl * 4;
        const Half4* gc = reinterpret_cast<const Half4*>(g) + cl;  // row stride 32 Half4
        float4 a0 = make_float4(0.f, 0.f, 0.f, 0.f), a1v = a0, a2 = a0, a3 = a0;

        if (half_ == 0) a0 = h4_to_f4(gc[(size_t)i * 32]);

        for (; e + 8 <= e1; e += 8) {
            int s0 = srcs[e + half_], s1 = srcs[e + 2 + half_];
            int s2 = srcs[e + 4 + half_], s3 = srcs[e + 6 + half_];
            float4 l0 = h4_to_f4(gc[(size_t)s0 * 32]);
            float4 l1 = h4_to_f4(gc[(size_t)s1 * 32]);
            float4 l2 = h4_to_f4(gc[(size_t)s2 * 32]);
            float4 l3 = h4_to_f4(gc[(size_t)s3 * 32]);
            a0.x += l0.x; a0.y += l0.y; a0.z += l0.z; a0.w += l0.w;
            a1v.x += l1.x; a1v.y += l1.y; a1v.z += l1.z; a1v.w += l1.w;
            a2.x += l2.x; a2.y += l2.y; a2.z += l2.z; a2.w += l2.w;
            a3.x += l3.x; a3.y += l3.y; a3.z += l3.z; a3.w += l3.w;
        }
        if (e + 4 <= e1) {
            int s0 = srcs[e + half_], s1 = srcs[e + 2 + half_];
            float4 l0 = h4_to_f4(gc[(size_t)s0 * 32]);
            float4 l1 = h4_to_f4(gc[(size_t)s1 * 32]);
            a0.x += l0.x; a0.y += l0.y; a0.z += l0.z; a0.w += l0.w;
            a1v.x += l1.x; a1v.y += l1.y; a1v.z += l1.z; a1v.w += l1.w;
            e += 4;
        }
        if (e + 2 <= e1) {
            int s0 = srcs[e + half_];
            float4 l0 = h4_to_f4(gc[(size_t)s0 * 32]);
            a2.x += l0.x; a2.y += l0.y; a2.z += l0.z; a2.w += l0.w;
            e += 2;
        }
        if (e < e1 && half_ == 0) {
            int s0 = srcs[e];
            float4 l0 = h4_to_f4(gc[(size_t)s0 * 32]);
            a3.x += l0.x; a3.y += l0.y; a3.z += l0.z; a3.w += l0.w;
        }

        float4 acc = make_float4((a0.x + a1v.x) + (a2.x + a3.x), (a0.y + a1v.y) + (a2.y + a3.y),
                                 (a0.z + a1v.z) + (a2.z + a3.z), (a0.w + a1v.w) + (a2.w + a3.w));
        acc.x += __shfl_xor(acc.x, 32, 64);
        acc.y += __shfl_xor(acc.y, 32, 64);
        acc.z += __shfl_xor(acc.z, 32, 64);
        acc.w += __shfl_xor(acc.w, 32, 64);

        if (half_ == 0) {
            float4 o = make_float4(di * acc.x, di * acc.y, di * acc.z, di * acc.w);
            if constexpr (BIAS) {
                float4 b = *reinterpret_cast<const float4*>(bias + c);
                o.x += b.x; o.y += b.y; o.z += b.z; o.w += b.w;
            }
            if constexpr (RELU) {
                o.x = fmaxf(o.x, 0.f); o.y = fmaxf(o.y, 0.f);
                o.z = fmaxf(o.z, 0.f); o.w = fmaxf(o.w, 0.f);
            }
            if constexpr (OUTH)
                *reinterpret_cast<Half4*>((__half*)outv + (size_t)i * C + c) = f4_to_h4(o);
            else
                *reinterpret_cast<float4*>((float*)outv + (size_t)i * C + c) = o;
        }
    } else {  // C == 64
        int grp = lane >> 4, cl = lane & 15, c = cl * 4;
        const Half4* gc = reinterpret_cast<const Half4*>(g) + cl;  // row stride 16 Half4
        float4 a0 = make_float4(0.f, 0.f, 0.f, 0.f), a1v = a0;

        if (grp == 0) a0 = h4_to_f4(gc[(size_t)i * 16]);

        for (; e + 8 <= e1; e += 8) {
            int s0 = srcs[e + grp], s1 = srcs[e + 4 + grp];
            float4 l0 = h4_to_f4(gc[(size_t)s0 * 16]);
            float4 l1 = h4_to_f4(gc[(size_t)s1 * 16]);
            a0.x += l0.x; a0.y += l0.y; a0.z += l0.z; a0.w += l0.w;
            a1v.x += l1.x; a1v.y += l1.y; a1v.z += l1.z; a1v.w += l1.w;
        }
        if (e + 4 <= e1) {
            int s0 = srcs[e + grp];
            float4 l0 = h4_to_f4(gc[(size_t)s0 * 16]);
            a0.x += l0.x; a0.y += l0.y; a0.z += l0.z; a0.w += l0.w;
            e += 4;
        }
        int rem = e1 - e;  // 0..3
        if (grp < rem) {
            int s0 = srcs[e + grp];
            float4 l0 = h4_to_f4(gc[(size_t)s0 * 16]);
            a1v.x += l0.x; a1v.y += l0.y; a1v.z += l0.z; a1v.w += l0.w;
        }

        float4 acc = make_float4(a0.x + a1v.x, a0.y + a1v.y, a0.z + a1v.z, a0.w + a1v.w);
        #pragma unroll
        for (int d = 16; d <= 32; d <<= 1) {
            acc.x += __shfl_xor(acc.x, d, 64);
            acc.y += __shfl_xor(acc.y, d, 64);
            acc.z += __shfl_xor(acc.z, d, 64);
            acc.w += __shfl_xor(acc.w, d, 64);
        }

        if (grp == 0) {
            float4 o = make_float4(di * acc.x, di * acc.y, di * acc.z, di * acc.w);
            if constexpr (BIAS) {
                float4 b = *reinterpret_cast<const float4*>(bias + c);
                o.x += b.x; o.y += b.y; o.z += b.z; o.w += b.w;
            }
            if constexpr (RELU) {
                o.x = fmaxf(o.x, 0.f); o.y = fmaxf(o.y, 0.f);
                o.z = fmaxf(o.z, 0.f); o.w = fmaxf(o.w, 0.f);
            }
            if constexpr (OUTH)
                *reinterpret_cast<Half4*>((__half*)outv + (size_t)i * C + c) = f4_to_h4(o);
            else
                *reinterpret_cast<float4*>((float*)outv + (size_t)i * C + c) = o;
        }
    }
}

// ---------------- pack all W into MFMA fragment order + zero bcnt (one kernel) ----------------
// frag layout (16x16x32 f16): lane l elem j -> k=(l>>4)*4+(j&3)+16*(j>>2), col=l&15.

template<int CIN, int COUT>
__device__ inline void pack_frag(const float* __restrict__ W, h8* __restrict__ Wp, int idx) {
    constexpr int NCT = COUT / 16;
    int l = idx & 63;
    int ct = (idx >> 6) % NCT;
    int ks = (idx >> 6) / NCT;
    int col = ct * 16 + (l & 15);
    int kb = ks * 32 + ((l >> 4) << 2);
    h8 t;
    #pragma unroll
    for (int j = 0; j < 8; ++j) {
        int k = kb + (j & 3) + ((j >> 2) << 4);
        t[j] = (_Float16)W[k * COUT + col];
    }
    Wp[idx] = t;
}

__global__ __launch_bounds__(256) void pack_all(const float* __restrict__ W1,
                                                const float* __restrict__ W2,
                                                const float* __restrict__ W3,
                                                h8* __restrict__ Wp1, h8* __restrict__ Wp2,
                                                h8* __restrict__ Wp3, int* __restrict__ bcnt) {
    int idx = blockIdx.x * 256 + threadIdx.x;
    if (idx < 1024)      pack_frag<64, 128>(W1, Wp1, idx);          // 2*8*64
    else if (idx < 3072) pack_frag<128, 128>(W2, Wp2, idx - 1024);  // 4*8*64
    else if (idx < 4096) pack_frag<128, 64>(W3, Wp3, idx - 3072);   // 4*4*64
    else {
        int z = idx - 4096;                                          // block 16: zero bcnt
        if (z < MAXNB) { bcnt[z] = 0; if (z + 256 < MAXNB) bcnt[z + 256] = 0; }
    }
}

// ---------------- MFMA GEMM: out = epilogue(A[n][CIN] @ W[CIN][COUT]) ----------------
// EPI 0: out = half(acc * aux[row]);  EPI 1: out = half(relu(acc + aux[col]))

template<int CIN, int COUT, int EPI>
__global__ __launch_bounds__(256) void mfma_gemm(const __half* __restrict__ A,
                                                 const h8* __restrict__ Wp,
                                                 const float* __restrict__ aux,
                                                 __half* __restrict__ out, int n) {
    constexpr int NKS = CIN / 32, NCT = COUT / 16;
    constexpr int FRAGS = NKS * NCT * 64;
    __shared__ h8 wlds[FRAGS];
    for (int idx = threadIdx.x; idx < FRAGS; idx += 256) wlds[idx] = Wp[idx];
    __syncthreads();

    int wid = threadIdx.x >> 6, lane = threadIdx.x & 63;
    int rowBase = blockIdx.x * 128 + wid * 32;
    int m = lane & 15;
    int kq = (lane >> 4) << 2;

    int row0 = min(rowBase + m, n - 1);
    int row1 = min(rowBase + 16 + m, n - 1);
    const __half* ar0 = A + (size_t)row0 * CIN;
    const __half* ar1 = A + (size_t)row1 * CIN;

    f32x4 acc[2][NCT];
    #pragma unroll
    for (int rt = 0; rt < 2; ++rt)
        #pragma unroll
        for (int ct = 0; ct < NCT; ++ct)
            acc[rt][ct] = f32x4{0.f, 0.f, 0.f, 0.f};

    #pragma unroll
    for (int ks = 0; ks < NKS; ++ks) {
        int kb = ks * 32 + kq;
        h8 a0, a1;
        *reinterpret_cast<short4*>(&a0) = *reinterpret_cast<const short4*>(ar0 + kb);
        *(reinterpret_cast<short4*>(&a0) + 1) = *reinterpret_cast<const short4*>(ar0 + kb + 16);
        *reinterpret_cast<short4*>(&a1) = *reinterpret_cast<const short4*>(ar1 + kb);
        *(reinterpret_cast<short4*>(&a1) + 1) = *reinterpret_cast<const short4*>(ar1 + kb + 16);
        #pragma unroll
        for (int ct = 0; ct < NCT; ++ct) {
            h8 b = wlds[(ks * NCT + ct) * 64 + lane];
            acc[0][ct] = __builtin_amdgcn_mfma_f32_16x16x32_f16(a0, b, acc[0][ct], 0, 0, 0);
            acc[1][ct] = __builtin_amdgcn_mfma_f32_16x16x32_f16(a1, b, acc[1][ct], 0, 0, 0);
        }
    }

    float bcol[NCT];
    if constexpr (EPI == 1) {
        #pragma unroll
        for (int ct = 0; ct < NCT; ++ct) bcol[ct] = aux[ct * 16 + m];
    }
    #pragma unroll
    for (int rt = 0; rt < 2; ++rt) {
        #pragma unroll
        for (int r = 0; r < 4; ++r) {
            int row = rowBase + rt * 16 + kq + r;
            if (row < n) {
                float d = 0.f;
                if constexpr (EPI == 0) d = aux[row];
                __half* orow = out + (size_t)row * COUT + m;
                #pragma unroll
                for (int ct = 0; ct < NCT; ++ct) {
                    float v = acc[rt][ct][r];
                    if constexpr (EPI == 0) v *= d;
                    else v = fmaxf(v + bcol[ct], 0.f);
                    orow[ct * 16] = __float2half(v);
                }
            }
        }
    }
}

// ---------------- launch ----------------

extern "C" void kernel_launch(void* const* d_in, const int* in_sizes, int n_in,
                              void* d_out, int out_size, void* d_ws, size_t ws_size,
                              hipStream_t stream) {
    const float* x  = (const float*)d_in[0];
    const int*   ei = (const int*)d_in[1];
    const float* W1 = (const float*)d_in[2];
    const float* b1 = (const float*)d_in[3];
    const float* W2 = (const float*)d_in[4];
    const float* b2 = (const float*)d_in[5];
    const float* W3 = (const float*)d_in[6];
    const float* b3 = (const float*)d_in[7];

    const int n = in_sizes[0] / 64;   // 50000
    const int e = in_sizes[1] / 2;    // 800000
    const int* src = ei;
    const int* dst = ei + e;
    const int nb = (n + 127) >> 7;    // 128-node buckets
    const bool packed = (n <= 65536);

    // workspace layout (4-byte units; 8B align for int2, 16B for h8)
    int*   ws_i = (int*)d_ws;
    float* ws_f = (float*)d_ws;
    size_t o = 0;
    int* bcnt    = ws_i + o; o += MAXNB;
    int* bbase   = ws_i + o; o += MAXNB + 2;
    int* bcursor = ws_i + o; o += MAXNB;
    int* offsets = ws_i + o; o += n + 8;
    int* srcs    = ws_i + o; o += e;
    float* dis   = ws_f + o; o += n;
    o = (o + 1) & ~(size_t)1;
    void* binned = (void*)(ws_i + o); o += (size_t)e * 2;  // reserve int2 worst case
    o = (o + 3) & ~(size_t)3;
    h8* Wp1 = (h8*)(ws_i + o); o += 4096;   // 1024 frags * 16B
    h8* Wp2 = (h8*)(ws_i + o); o += 8192;   // 2048 frags
    h8* Wp3 = (h8*)(ws_i + o); o += 4096;   // 1024 frags
    float* R1 = ws_f + o; o += (size_t)n * 64;   // a1h (n*64 h), then h2h (n*128 h)
    float* R2 = ws_f + o; o += (size_t)n * 64;   // h1h (n*128 h), then g3 (n*64 h)

    // d_out doubles as scratch: x16 (half 64w), then g2 (half 128w), then final out
    Half4*  x16 = (Half4*)d_out;
    __half* g2  = (__half*)d_out;
    __half* a1h = (__half*)R1;
    __half* h1h = (__half*)R2;
    __half* h2h = (__half*)R1;
    __half* g3  = (__half*)R2;
    float*  out = (float*)d_out;

    const int B = 256;
    // pack weights + zero bcnt (block 16), strictly before bucket_count in stream order
    pack_all<<<17, B, 0, stream>>>(W1, W2, W3, Wp1, Wp2, Wp3, bcnt);
    // CSR build (two-level counting sort) + x16 prep
    bucket_count<<<256, B, 0, stream>>>(dst, bcnt, e, nb);
    scan_buckets<<<1, 64, 0, stream>>>(bcnt, bbase, bcursor, nb);
    if (packed) {
        bin_edges<true><<<(e + R3_CHUNK - 1) / R3_CHUNK, B, 0, stream>>>(src, dst, bcursor, binned, e, nb);
        finalize_csr<true><<<nb, 128, 0, stream>>>(binned, bbase, offsets, srcs, dis, x, x16, n, nb);
    } else {
        bin_edges<false><<<(e + R3_CHUNK - 1) / R3_CHUNK, B, 0, stream>>>(src, dst, bcursor, binned, e, nb);
        finalize_csr<false><<<nb, 128, 0, stream>>>(binned, bbase, offsets, srcs, dis, x, x16, n, nb);
    }

    dim3 agrid((n + 3) / 4);
    dim3 ggrid((n + 127) / 128);

    // L1: a1h = half(dis*agg(x16)); h1h = half(relu(a1@W1+b1))
    aggregate_h<64, false, false, true><<<agrid, 256, 0, stream>>>((const __half*)x16, srcs, offsets, dis, nullptr, a1h, n);
    mfma_gemm<64, 128, 1><<<ggrid, 256, 0, stream>>>(a1h, Wp1, b1, h1h, n);
    // L2: g2 = half((h1@W2)*dis); h2h = half(relu(dis*agg(g2)+b2))
    mfma_gemm<128, 128, 0><<<ggrid, 256, 0, stream>>>(h1h, Wp2, dis, g2, n);
    aggregate_h<128, true, true, true><<<agrid, 256, 0, stream>>>(g2, srcs, offsets, dis, b2, h2h, n);
    // L3: g3 = half((h2@W3)*dis); out = dis*agg(g3)+b3
    mfma_gemm<128, 64, 0><<<ggrid, 256, 0, stream>>>(h2h, Wp3, dis, g3, n);
    aggregate_h<64, false, true, false><<<agrid, 256, 0, stream>>>(g3, srcs, offsets, dis, b3, out, n);
}

// Round 11
// 168.172 us; speedup vs baseline: 2.4021x; 1.0388x over previous
//
#include <hip/hip_runtime.h>
#include <hip/hip_fp16.h>

// GCN 3-layer, fp16 payloads + MFMA GEMMs (f32 accumulate):
// L1: a1h = half(dis.*agg(x16)) ; h1h = half(relu(a1@W1+b1))   [agg64h + mfma_gemm EPI1]
// L2: g2 = half((h1@W2).*dis)   ; h2h = half(relu(dis.*agg(g2)+b2)) [mfma EPI0 + agg128h]
// L3: g3 = half((h2@W3).*dis)   ; out = dis.*agg(g3)+b3        [mfma EPI0 + agg64h f32]
// dis[i] = rsqrt(1 + indegree[i]); x16 = half(x .* dis) produced inside finalize_csr.
// CSR: two-level counting sort (128-node buckets); packed 4B records + u16 srcs (n<=65536).
// Aggregates: 16-B (h8) row loads — 16 lanes/row (C=128) or 8 lanes/row (C=64).

typedef _Float16 h8 __attribute__((ext_vector_type(8)));
typedef float f32x4 __attribute__((ext_vector_type(4)));

struct alignas(8) Half4 { __half2 lo, hi; };

__device__ inline Half4 f4_to_h4(float4 v) {
    Half4 h; h.lo = __floats2half2_rn(v.x, v.y); h.hi = __floats2half2_rn(v.z, v.w); return h;
}

#define MAXNB 512   // buckets of 128 nodes; covers n <= 65536

// ---------------- R1: bucket histogram ----------------

__global__ __launch_bounds__(256) void bucket_count(const int* __restrict__ dst,
                                                    int* __restrict__ bcnt, int e, int nb) {
    __shared__ int h[MAXNB];
    int tid = threadIdx.x;
    for (int i = tid; i < nb; i += 256) h[i] = 0;
    __syncthreads();
    for (int i = blockIdx.x * 256 + tid; i < e; i += gridDim.x * 256)
        atomicAdd(&h[dst[i] >> 7], 1);
    __syncthreads();
    for (int i = tid; i < nb; i += 256) {
        int c = h[i];
        if (c) atomicAdd(&bcnt[i], c);
    }
}

// ---------------- R2: single-wave exclusive scan of bucket counts ----------------

__global__ void scan_buckets(const int* __restrict__ bcnt, int* __restrict__ bbase,
                             int* __restrict__ bcursor, int nb) {
    int lane = threadIdx.x;  // 64 threads
    int running = 0;
    for (int base = 0; base < nb; base += 64) {
        int idx = base + lane;
        int v = (idx < nb) ? bcnt[idx] : 0;
        int x = v;
        #pragma unroll
        for (int d = 1; d < 64; d <<= 1) {
            int t = __shfl_up(x, d, 64);
            if (lane >= d) x += t;
        }
        if (idx < nb) { bbase[idx] = running + x - v; bcursor[idx] = running + x - v; }
        running += __shfl(x, 63, 64);
    }
    if (lane == 0) bbase[nb] = running;
}

// ---------------- R3: bin edges into bucket segments ----------------
// PACKED (n<=65536): record = src | (dst&127)<<16  (4 B). Else int2 (src,dst).

#define R3_CHUNK 4096

template<bool PACKED>
__global__ __launch_bounds__(256) void bin_edges(const int* __restrict__ src,
                                                 const int* __restrict__ dst,
                                                 int* __restrict__ bcursor,
                                                 void* __restrict__ binned_, int e, int nb) {
    __shared__ int h[MAXNB];
    __shared__ int gp[MAXNB];
    int tid = threadIdx.x;
    for (int i = tid; i < nb; i += 256) h[i] = 0;
    __syncthreads();
    int lo = blockIdx.x * R3_CHUNK, hi = min(lo + R3_CHUNK, e);
    for (int i = lo + tid; i < hi; i += 256) atomicAdd(&h[dst[i] >> 7], 1);
    __syncthreads();
    for (int b = tid; b < nb; b += 256) {
        int c = h[b];
        if (c) gp[b] = atomicAdd(&bcursor[b], c);
        h[b] = 0;  // reuse as local cursor
    }
    __syncthreads();
    for (int i = lo + tid; i < hi; i += 256) {
        int d = dst[i];
        int b = d >> 7;
        int p = atomicAdd(&h[b], 1);
        if constexpr (PACKED)
            ((unsigned*)binned_)[gp[b] + p] = (unsigned)src[i] | ((unsigned)(d & 127) << 16);
        else
            ((int2*)binned_)[gp[b] + p] = make_int2(src[i], d);
    }
}

// ---------------- R4: per-bucket finalize + x16 conversion ----------------
// PACKED: srcs written as u16; else as int.

template<bool PACKED>
__global__ __launch_bounds__(128) void finalize_csr(const void* __restrict__ binned_,
                                                    const int* __restrict__ bbase,
                                                    int* __restrict__ offsets,
                                                    void* __restrict__ srcs_,
                                                    float* __restrict__ dis,
                                                    const float* __restrict__ x,
                                                    Half4* __restrict__ x16,
                                                    int n, int nb) {
    int b = blockIdx.x;
    int tid = threadIdx.x;  // 128 threads, one node each
    int nb0 = b << 7;
    int segLo = bbase[b], segHi = bbase[b + 1];

    __shared__ int cnt[128];
    __shared__ int cur[128];
    __shared__ float sdis[128];
    __shared__ int wtot;
    cnt[tid] = 0;
    __syncthreads();
    if constexpr (PACKED) {
        const unsigned* binned = (const unsigned*)binned_;
        for (int i = segLo + tid; i < segHi; i += 128)
            atomicAdd(&cnt[(binned[i] >> 16) & 127], 1);
    } else {
        const int2* binned = (const int2*)binned_;
        for (int i = segLo + tid; i < segHi; i += 128)
            atomicAdd(&cnt[binned[i].y & 127], 1);
    }
    __syncthreads();

    int c = cnt[tid];
    int lane = tid & 63, w = tid >> 6;
    int x_ = c;
    #pragma unroll
    for (int d = 1; d < 64; d <<= 1) {
        int t = __shfl_up(x_, d, 64);
        if (lane >= d) x_ += t;
    }
    if (w == 0 && lane == 63) wtot = x_;
    __syncthreads();
    int excl = x_ - c + (w ? wtot : 0);

    int node = nb0 + tid;
    float dv = rsqrtf((float)(c + 1));
    if (node < n) {
        offsets[node] = segLo + excl;
        dis[node] = dv;
    }
    if (b == nb - 1 && tid == 0) offsets[n] = segHi;
    cur[tid] = excl;
    sdis[tid] = dv;
    __syncthreads();

    if constexpr (PACKED) {
        const unsigned* binned = (const unsigned*)binned_;
        unsigned short* srcs = (unsigned short*)srcs_;
        for (int i = segLo + tid; i < segHi; i += 128) {
            unsigned v = binned[i];
            int ln = (v >> 16) & 127;
            int p = atomicAdd(&cur[ln], 1);
            srcs[segLo + p] = (unsigned short)(v & 0xFFFFu);
        }
    } else {
        const int2* binned = (const int2*)binned_;
        int* srcs = (int*)srcs_;
        for (int i = segLo + tid; i < segHi; i += 128) {
            int2 v = binned[i];
            int ln = v.y & 127;
            int p = atomicAdd(&cur[ln], 1);
            srcs[segLo + p] = v.x;
        }
    }

    // x16 rows for this bucket's nodes: x16[node] = half(x[node] * dis[node])
    int rows = min(128, n - nb0);
    if (rows > 0) {
        int limit = rows * 16;  // Half4 units (64 ch = 16 Half4)
        const float4* xr = reinterpret_cast<const float4*>(x) + (size_t)nb0 * 16;
        Half4* xo = x16 + (size_t)nb0 * 16;
        for (int idx = tid; idx < limit; idx += 128) {
            float d = sdis[idx >> 4];
            float4 v = xr[idx];
            xo[idx] = f4_to_h4(make_float4(v.x * d, v.y * d, v.z * d, v.w * d));
        }
    }
}

// ---------------- aggregate (fp16 payload, 16B row loads, f32 accumulate) ----------------
// out[i] = [relu]( dis[i]*( g[i] + sum_edges g[s] ) [+ bias] ), payloads prescaled.
// C=128: 4 groups of 16 lanes (16B/lane/row); C=64: 8 groups of 8 lanes.
// IT: index type (u16 when n<=65536, else int). OUTH: half output.

template<int C, bool RELU, bool BIAS, bool OUTH, typename IT>
__global__ __launch_bounds__(256) void aggregate_h(const __half* __restrict__ g,
                                                   const IT* __restrict__ srcs,
                                                   const int* __restrict__ offsets,
                                                   const float* __restrict__ dis,
                                                   const float* __restrict__ bias,
                                                   void* __restrict__ outv, int n) {
    constexpr int LPR = C / 8;           // lanes per row (16B = 8 halves each)
    constexpr int NG = 64 / LPR;         // groups (edges in flight per step)
    constexpr int RSTRIDE = C / 8;       // row stride in h8 units
    int wid = threadIdx.x >> 6, lane = threadIdx.x & 63;
    int i = blockIdx.x * 4 + wid;
    if (i >= n) return;
    float di = dis[i];
    int e0 = offsets[i], e1 = offsets[i + 1];
    int e = e0;

    int grp = lane / LPR, cl = lane % LPR;
    const h8* gc = reinterpret_cast<const h8*>(g) + cl;

    float a0[8], a1[8];
    #pragma unroll
    for (int j = 0; j < 8; ++j) { a0[j] = 0.f; a1[j] = 0.f; }

    if (grp == 0) {
        h8 v = gc[(size_t)i * RSTRIDE];
        #pragma unroll
        for (int j = 0; j < 8; ++j) a0[j] = (float)v[j];
    }

    for (; e + 2 * NG <= e1; e += 2 * NG) {
        int s0 = (int)srcs[e + grp], s1 = (int)srcs[e + NG + grp];
        h8 l0 = gc[(size_t)s0 * RSTRIDE];
        h8 l1 = gc[(size_t)s1 * RSTRIDE];
        #pragma unroll
        for (int j = 0; j < 8; ++j) { a0[j] += (float)l0[j]; a1[j] += (float)l1[j]; }
    }
    if (e + NG <= e1) {
        int s0 = (int)srcs[e + grp];
        h8 l0 = gc[(size_t)s0 * RSTRIDE];
        #pragma unroll
        for (int j = 0; j < 8; ++j) a0[j] += (float)l0[j];
        e += NG;
    }
    int rem = e1 - e;  // 0..NG-1
    if (grp < rem) {
        int s0 = (int)srcs[e + grp];
        h8 l0 = gc[(size_t)s0 * RSTRIDE];
        #pragma unroll
        for (int j = 0; j < 8; ++j) a1[j] += (float)l0[j];
    }

    float acc[8];
    #pragma unroll
    for (int j = 0; j < 8; ++j) acc[j] = a0[j] + a1[j];
    #pragma unroll
    for (int d = LPR; d < 64; d <<= 1) {
        #pragma unroll
        for (int j = 0; j < 8; ++j) acc[j] += __shfl_xor(acc[j], d, 64);
    }

    if (grp == 0) {
        int c = cl * 8;
        float o[8];
        #pragma unroll
        for (int j = 0; j < 8; ++j) {
            float t = di * acc[j];
            if constexpr (BIAS) t += bias[c + j];
            if constexpr (RELU) t = fmaxf(t, 0.f);
            o[j] = t;
        }
        if constexpr (OUTH) {
            h8 hv;
            #pragma unroll
            for (int j = 0; j < 8; ++j) hv[j] = (_Float16)o[j];
            reinterpret_cast<h8*>((__half*)outv)[(size_t)i * RSTRIDE + cl] = hv;
        } else {
            float* op = (float*)outv + (size_t)i * C + c;
            *reinterpret_cast<float4*>(op) = make_float4(o[0], o[1], o[2], o[3]);
            *reinterpret_cast<float4*>(op + 4) = make_float4(o[4], o[5], o[6], o[7]);
        }
    }
}

// ---------------- pack all W into MFMA fragment order + zero bcnt (one kernel) ----------------
// frag layout (16x16x32 f16): lane l elem j -> k=(l>>4)*4+(j&3)+16*(j>>2), col=l&15.

template<int CIN, int COUT>
__device__ inline void pack_frag(const float* __restrict__ W, h8* __restrict__ Wp, int idx) {
    constexpr int NCT = COUT / 16;
    int l = idx & 63;
    int ct = (idx >> 6) % NCT;
    int ks = (idx >> 6) / NCT;
    int col = ct * 16 + (l & 15);
    int kb = ks * 32 + ((l >> 4) << 2);
    h8 t;
    #pragma unroll
    for (int j = 0; j < 8; ++j) {
        int k = kb + (j & 3) + ((j >> 2) << 4);
        t[j] = (_Float16)W[k * COUT + col];
    }
    Wp[idx] = t;
}

__global__ __launch_bounds__(256) void pack_all(const float* __restrict__ W1,
                                                const float* __restrict__ W2,
                                                const float* __restrict__ W3,
                                                h8* __restrict__ Wp1, h8* __restrict__ Wp2,
                                                h8* __restrict__ Wp3, int* __restrict__ bcnt) {
    int idx = blockIdx.x * 256 + threadIdx.x;
    if (idx < 1024)      pack_frag<64, 128>(W1, Wp1, idx);          // 2*8*64
    else if (idx < 3072) pack_frag<128, 128>(W2, Wp2, idx - 1024);  // 4*8*64
    else if (idx < 4096) pack_frag<128, 64>(W3, Wp3, idx - 3072);   // 4*4*64
    else {
        int z = idx - 4096;                                          // block 16: zero bcnt
        if (z < MAXNB) { bcnt[z] = 0; if (z + 256 < MAXNB) bcnt[z + 256] = 0; }
    }
}

// ---------------- MFMA GEMM: out = epilogue(A[n][CIN] @ W[CIN][COUT]) ----------------
// EPI 0: out = half(acc * aux[row]);  EPI 1: out = half(relu(acc + aux[col]))

template<int CIN, int COUT, int EPI>
__global__ __launch_bounds__(256) void mfma_gemm(const __half* __restrict__ A,
                                                 const h8* __restrict__ Wp,
                                                 const float* __restrict__ aux,
                                                 __half* __restrict__ out, int n) {
    constexpr int NKS = CIN / 32, NCT = COUT / 16;
    constexpr int FRAGS = NKS * NCT * 64;
    __shared__ h8 wlds[FRAGS];
    for (int idx = threadIdx.x; idx < FRAGS; idx += 256) wlds[idx] = Wp[idx];
    __syncthreads();

    int wid = threadIdx.x >> 6, lane = threadIdx.x & 63;
    int rowBase = blockIdx.x * 128 + wid * 32;
    int m = lane & 15;
    int kq = (lane >> 4) << 2;

    int row0 = min(rowBase + m, n - 1);
    int row1 = min(rowBase + 16 + m, n - 1);
    const __half* ar0 = A + (size_t)row0 * CIN;
    const __half* ar1 = A + (size_t)row1 * CIN;

    f32x4 acc[2][NCT];
    #pragma unroll
    for (int rt = 0; rt < 2; ++rt)
        #pragma unroll
        for (int ct = 0; ct < NCT; ++ct)
            acc[rt][ct] = f32x4{0.f, 0.f, 0.f, 0.f};

    #pragma unroll
    for (int ks = 0; ks < NKS; ++ks) {
        int kb = ks * 32 + kq;
        h8 a0, a1;
        *reinterpret_cast<short4*>(&a0) = *reinterpret_cast<const short4*>(ar0 + kb);
        *(reinterpret_cast<short4*>(&a0) + 1) = *reinterpret_cast<const short4*>(ar0 + kb + 16);
        *reinterpret_cast<short4*>(&a1) = *reinterpret_cast<const short4*>(ar1 + kb);
        *(reinterpret_cast<short4*>(&a1) + 1) = *reinterpret_cast<const short4*>(ar1 + kb + 16);
        #pragma unroll
        for (int ct = 0; ct < NCT; ++ct) {
            h8 b = wlds[(ks * NCT + ct) * 64 + lane];
            acc[0][ct] = __builtin_amdgcn_mfma_f32_16x16x32_f16(a0, b, acc[0][ct], 0, 0, 0);
            acc[1][ct] = __builtin_amdgcn_mfma_f32_16x16x32_f16(a1, b, acc[1][ct], 0, 0, 0);
        }
    }

    float bcol[NCT];
    if constexpr (EPI == 1) {
        #pragma unroll
        for (int ct = 0; ct < NCT; ++ct) bcol[ct] = aux[ct * 16 + m];
    }
    #pragma unroll
    for (int rt = 0; rt < 2; ++rt) {
        #pragma unroll
        for (int r = 0; r < 4; ++r) {
            int row = rowBase + rt * 16 + kq + r;
            if (row < n) {
                float d = 0.f;
                if constexpr (EPI == 0) d = aux[row];
                __half* orow = out + (size_t)row * COUT + m;
                #pragma unroll
                for (int ct = 0; ct < NCT; ++ct) {
                    float v = acc[rt][ct][r];
                    if constexpr (EPI == 0) v *= d;
                    else v = fmaxf(v + bcol[ct], 0.f);
                    orow[ct * 16] = __float2half(v);
                }
            }
        }
    }
}

// ---------------- launch ----------------

extern "C" void kernel_launch(void* const* d_in, const int* in_sizes, int n_in,
                              void* d_out, int out_size, void* d_ws, size_t ws_size,
                              hipStream_t stream) {
    const float* x  = (const float*)d_in[0];
    const int*   ei = (const int*)d_in[1];
    const float* W1 = (const float*)d_in[2];
    const float* b1 = (const float*)d_in[3];
    const float* W2 = (const float*)d_in[4];
    const float* b2 = (const float*)d_in[5];
    const float* W3 = (const float*)d_in[6];
    const float* b3 = (const float*)d_in[7];

    const int n = in_sizes[0] / 64;   // 50000
    const int e = in_sizes[1] / 2;    // 800000
    const int* src = ei;
    const int* dst = ei + e;
    const int nb = (n + 127) >> 7;    // 128-node buckets
    const bool packed = (n <= 65536);

    // workspace layout (4-byte units; 8B align for int2, 16B for h8)
    int*   ws_i = (int*)d_ws;
    float* ws_f = (float*)d_ws;
    size_t o = 0;
    int* bcnt    = ws_i + o; o += MAXNB;
    int* bbase   = ws_i + o; o += MAXNB + 2;
    int* bcursor = ws_i + o; o += MAXNB;
    int* offsets = ws_i + o; o += n + 8;
    void* srcs   = (void*)(ws_i + o); o += e;   // u16 when packed (uses half), int otherwise
    float* dis   = ws_f + o; o += n;
    o = (o + 1) & ~(size_t)1;
    void* binned = (void*)(ws_i + o); o += (size_t)e * 2;  // reserve int2 worst case
    o = (o + 3) & ~(size_t)3;
    h8* Wp1 = (h8*)(ws_i + o); o += 4096;   // 1024 frags * 16B
    h8* Wp2 = (h8*)(ws_i + o); o += 8192;   // 2048 frags
    h8* Wp3 = (h8*)(ws_i + o); o += 4096;   // 1024 frags
    float* R1 = ws_f + o; o += (size_t)n * 64;   // a1h (n*64 h), then h2h (n*128 h)
    float* R2 = ws_f + o; o += (size_t)n * 64;   // h1h (n*128 h), then g3 (n*64 h)

    // d_out doubles as scratch: x16 (half 64w), then g2 (half 128w), then final out
    Half4*  x16 = (Half4*)d_out;
    __half* g2  = (__half*)d_out;
    __half* a1h = (__half*)R1;
    __half* h1h = (__half*)R2;
    __half* h2h = (__half*)R1;
    __half* g3  = (__half*)R2;
    float*  out = (float*)d_out;

    const int B = 256;
    // pack weights + zero bcnt (block 16), strictly before bucket_count in stream order
    pack_all<<<17, B, 0, stream>>>(W1, W2, W3, Wp1, Wp2, Wp3, bcnt);
    // CSR build (two-level counting sort) + x16 prep
    bucket_count<<<256, B, 0, stream>>>(dst, bcnt, e, nb);
    scan_buckets<<<1, 64, 0, stream>>>(bcnt, bbase, bcursor, nb);

    dim3 agrid((n + 3) / 4);
    dim3 ggrid((n + 127) / 128);

    if (packed) {
        bin_edges<true><<<(e + R3_CHUNK - 1) / R3_CHUNK, B, 0, stream>>>(src, dst, bcursor, binned, e, nb);
        finalize_csr<true><<<nb, 128, 0, stream>>>(binned, bbase, offsets, srcs, dis, x, x16, n, nb);
        const unsigned short* s16 = (const unsigned short*)srcs;
        aggregate_h<64, false, false, true, unsigned short><<<agrid, 256, 0, stream>>>((const __half*)x16, s16, offsets, dis, nullptr, a1h, n);
        mfma_gemm<64, 128, 1><<<ggrid, 256, 0, stream>>>(a1h, Wp1, b1, h1h, n);
        mfma_gemm<128, 128, 0><<<ggrid, 256, 0, stream>>>(h1h, Wp2, dis, g2, n);
        aggregate_h<128, true, true, true, unsigned short><<<agrid, 256, 0, stream>>>(g2, s16, offsets, dis, b2, h2h, n);
        mfma_gemm<128, 64, 0><<<ggrid, 256, 0, stream>>>(h2h, Wp3, dis, g3, n);
        aggregate_h<64, false, true, false, unsigned short><<<agrid, 256, 0, stream>>>(g3, s16, offsets, dis, b3, out, n);
    } else {
        bin_edges<false><<<(e + R3_CHUNK - 1) / R3_CHUNK, B, 0, stream>>>(src, dst, bcursor, binned, e, nb);
        finalize_csr<false><<<nb, 128, 0, stream>>>(binned, bbase, offsets, srcs, dis, x, x16, n, nb);
        const int* s32 = (const int*)srcs;
        aggregate_h<64, false, false, true, int><<<agrid, 256, 0, stream>>>((const __half*)x16, s32, offsets, dis, nullptr, a1h, n);
        mfma_gemm<64, 128, 1><<<ggrid, 256, 0, stream>>>(a1h, Wp1, b1, h1h, n);
        mfma_gemm<128, 128, 0><<<ggrid, 256, 0, stream>>>(h1h, Wp2, dis, g2, n);
        aggregate_h<128, true, true, true, int><<<agrid, 256, 0, stream>>>(g2, s32, offsets, dis, b2, h2h, n);
        mfma_gemm<128, 64, 0><<<ggrid, 256, 0, stream>>>(h2h, Wp3, dis, g3, n);
        aggregate_h<64, false, true, false, int><<<agrid, 256, 0, stream>>>(g3, s32, offsets, dis, b3, out, n);
    }
}